// Round 19
// baseline (263.769 us; speedup 1.0000x reference)
//
#include <hip/hip_runtime.h>
#include <cstdint>
#include <cstddef>

#define TOK    32768   // B*L
#define BATCH  8
#define SEQ    4096
#define DMODEL 256
#define DINNER 512
#define DSTATE 64
#define NH     16
#define HD     32
#define DPROJ  1168
#define NPAD   1152    // in_proj N: z(512)+xBC(640); dt computed in k_embed
#define CONVD  640
#define VOCAB  512
#define HGRP   4       // heads per states/y block
#define TS     132     // conv tile LDS stride (shorts)

typedef __attribute__((ext_vector_type(8))) short bf16x8;
typedef __attribute__((ext_vector_type(4))) float f32x4;

__device__ __forceinline__ unsigned short f2bf(float f) {
    unsigned u = __float_as_uint(f);
    u += 0x7fffu + ((u >> 16) & 1u);       // RNE
    return (unsigned short)(u >> 16);
}
__device__ __forceinline__ float bf2f(short s) {
    return __uint_as_float(((unsigned)(unsigned short)s) << 16);
}
// pack two f32 -> two bf16 (RNE) in one instruction
__device__ __forceinline__ unsigned cvtpk(float lo, float hi) {
    unsigned r;
    asm("v_cvt_pk_bf16_f32 %0, %1, %2" : "=v"(r) : "v"(lo), "v"(hi));
    return r;
}
__device__ __forceinline__ float fsilu(float s) {
    return s * __builtin_amdgcn_rcpf(1.f + __expf(-s));
}
__device__ __forceinline__ float sp(float v) {
    return v > 20.f ? v : __logf(1.f + __expf(v));
}

// async global->LDS, 16B per lane; dst wave-uniform base, lane fills dst+lane*16B
__device__ __forceinline__ void gload16(const short* src, short* dst) {
    __builtin_amdgcn_global_load_lds((const __attribute__((address_space(1))) void*)src,
                                     (__attribute__((address_space(3))) void*)dst, 16, 0, 0);
}

// ---------------- ws layout (floats, all 16B aligned) ----------------
#define U16_OFF   0                                    // TOK*256 bf16
#define Z16_OFF   (U16_OFF  + (size_t)TOK*128)         // TOK*512 bf16
#define XBC_OFF   (Z16_OFF  + (size_t)TOK*256)         // TOK*640 bf16
#define DTS_OFF   (XBC_OFF  + (size_t)TOK*320)         // TOK*16 fp32
#define ACS_OFF   (DTS_OFF  + (size_t)TOK*16)
#define CDEC_OFF  (ACS_OFF  + (size_t)BATCH*NH*64*64)
#define WP_OFF    (CDEC_OFF + (size_t)BATCH*NH*64)
#define WO_OFF    (WP_OFF   + 163840)
#define WE_OFF    (WO_OFF   + 65536)
#define UNION_OFF (WE_OFF   + 65536)
// union: [0,TOK*256): st16 bf16 (dead after k_y) -> xf16 bf16
//        [TOK*256,TOK*512): Y16 bf16 (read by k_outproj)
#define UNION_FL  ((size_t)BATCH*64*NH*2048)
#define Y16_SUB   ((size_t)TOK*256)
#define WS_FLOATS (UNION_OFF + UNION_FL)

__global__ void k_diag(float* out, float wsmb) {
    if (blockIdx.x == 0 && threadIdx.x == 0) out[0] = wsmb;
}

// ---------------- weight fp32 -> bf16 (+ zero pad) ----------------
__global__ void k_cvt(const float* __restrict__ s, short* __restrict__ d, int nsrc, int ntot) {
    int i = blockIdx.x * 256 + threadIdx.x;
    if (i < ntot) d[i] = (i < nsrc) ? (short)f2bf(s[i]) : (short)0;
}
// Wo' = Wo * gate_norm_w (folded gate weight; K = DINNER, power of 2)
__global__ void k_cvt_gate(const float* __restrict__ s, const float* __restrict__ gw,
                           short* __restrict__ d, int ntot) {
    int i = blockIdx.x * 256 + threadIdx.x;
    if (i < ntot) d[i] = (short)f2bf(s[i] * gw[i & (DINNER - 1)]);
}

// ---------------- embed gather + rmsnorm -> u16 (bf16) + dt = softplus(u.Wdt + bias) ----------------
__global__ void k_embed(const int* __restrict__ ids, const float* __restrict__ embed,
                        const float* __restrict__ norm_w, const float* __restrict__ in_proj_w,
                        const float* __restrict__ dt_bias, short* __restrict__ u16,
                        float* __restrict__ dts) {
    __shared__ float uS[DMODEL];
    int t = blockIdx.x;
    int lane = threadIdx.x;   // 64
    int id = ids[t];
    float4 v = ((const float4*)(embed + (size_t)id * DMODEL))[lane];
    float ss = v.x*v.x + v.y*v.y + v.z*v.z + v.w*v.w;
    #pragma unroll
    for (int o = 32; o > 0; o >>= 1) ss += __shfl_down(ss, o);
    ss = __shfl(ss, 0);
    float r = rsqrtf(ss * (1.0f / DMODEL) + 1e-6f);
    float4 w = ((const float4*)norm_w)[lane];
    float u0 = v.x * r * w.x, u1 = v.y * r * w.y, u2 = v.z * r * w.z, u3 = v.w * r * w.w;
    ((uint2*)(u16 + (size_t)t * DMODEL))[lane] = make_uint2(cvtpk(u0, u1), cvtpk(u2, u3));
    ((float4*)uS)[lane] = make_float4(u0, u1, u2, u3);
    __syncthreads();
    // dt: 4 lanes per head; sub-range of 64 k each; fp32 weights from in_proj rows 1152+h
    int h = lane >> 2, sub = lane & 3;
    const float4* wd = (const float4*)(in_proj_w + (size_t)(1152 + h) * DMODEL + sub * 64);
    const float4* us = (const float4*)(uS + sub * 64);
    float s = 0.f;
    #pragma unroll
    for (int k4 = 0; k4 < 16; k4++) {
        float4 a = us[k4], b = wd[k4];
        s += a.x * b.x + a.y * b.y + a.z * b.z + a.w * b.w;
    }
    s += __shfl_xor(s, 1);
    s += __shfl_xor(s, 2);
    if (sub == 0) dts[(size_t)t * NH + h] = sp(s + dt_bias[h]);
}

// ---------------- bf16 MFMA GEMM: 512 threads (8 waves), 128x128 tile, BK=64 ----------------
// Single 32KB LDS buffer, two barriers/iter (R17 structure — best known for this K).
// Rule-#21 swizzle; XCD-aware tile map (T1).
// MODE 0: in_proj N=1152 (z16 / conv+silu->xbc).  MODE 2: logits fp32.
template<int MODE>
__global__ __launch_bounds__(512) void k_gemm_mfma(
    const short* __restrict__ A, const short* __restrict__ B, int K,
    float* __restrict__ outF, short* __restrict__ z16, short* __restrict__ xbc,
    const float* __restrict__ cw, const float* __restrict__ cb) {
    // A (8192 shorts) | B (8192 shorts); MODE 0 conv Tile aliases (131*TS = 17292)
    __shared__ __align__(16) short SM[MODE == 0 ? (131 * TS) : 16384];
    constexpr int NX = (MODE == 0) ? (NPAD / 128) : (VOCAB / 128);
    int tid = threadIdx.x;
    int bid = blockIdx.x;
    int slot = bid >> 3;
    int m0 = (((bid & 7) * 32) + slot / NX) << 7;
    int n0 = (slot % NX) << 7;
    int wave = tid >> 6, lane = tid & 63;
    int wm = wave >> 1, wn = wave & 1;
    int lr = lane & 15, lg = lane >> 4;
    const f32x4 zer = {0.f, 0.f, 0.f, 0.f};
    f32x4 acc[2][4];
    #pragma unroll
    for (int i = 0; i < 2; i++)
        #pragma unroll
        for (int j = 0; j < 4; j++) acc[i][j] = zer;

    const bool isXBC = (MODE == 0) && (n0 >= 512);
    const bool atStart = (m0 & (SEQ - 1)) == 0;
    const bool haloLane = isXBC && (wm == 0) && !atStart && (lr < 3);
    f32x4 hacc[4];
    #pragma unroll
    for (int j = 0; j < 4; j++) hacc[j] = zer;
    const bf16x8 hz = {0, 0, 0, 0, 0, 0, 0, 0};
    bf16x8 hc0 = hz, hc1 = hz, hn0 = hz, hn1 = hz;

    const int nK = K >> 6;
    const int slo = lane >> 3;
    const int skb = ((lane & 7) ^ slo) << 3;

    // prologue: stage tile 0 (+halo regs)
    {
        #pragma unroll
        for (int j = 0; j < 2; j++) {
            int row = wave * 16 + j * 8 + slo;
            gload16(A + (size_t)(m0 + row) * K + skb, SM + (wave * 2 + j) * 512);
            gload16(B + (size_t)(n0 + row) * K + skb, SM + 8192 + (wave * 2 + j) * 512);
        }
        if (haloLane) {
            hc0 = *(const bf16x8*)(A + (size_t)(m0 - 3 + lr) * K + lg * 8);
            hc1 = *(const bf16x8*)(A + (size_t)(m0 - 3 + lr) * K + 32 + lg * 8);
        }
    }
    __syncthreads();   // drains vmcnt: tile 0 ready

    for (int kt = 0; kt < nK; ++kt) {
        #pragma unroll
        for (int kk = 0; kk < 2; kk++) {
            int sw = (((kk << 2) + lg) ^ (lr & 7)) << 3;
            bf16x8 af[2], bfr[4];
            #pragma unroll
            for (int mi = 0; mi < 2; mi++)
                af[mi] = *(const bf16x8*)&SM[(wm * 32 + mi * 16 + lr) * 64 + sw];
            #pragma unroll
            for (int ni = 0; ni < 4; ni++)
                bfr[ni] = *(const bf16x8*)&SM[8192 + (wn * 64 + ni * 16 + lr) * 64 + sw];
            #pragma unroll
            for (int mi = 0; mi < 2; mi++)
                #pragma unroll
                for (int ni = 0; ni < 4; ni++)
                    acc[mi][ni] = __builtin_amdgcn_mfma_f32_16x16x32_bf16(af[mi], bfr[ni], acc[mi][ni], 0, 0, 0);
            if (isXBC && wm == 0) {
                bf16x8 h = (kk == 0) ? hc0 : hc1;
                #pragma unroll
                for (int ni = 0; ni < 4; ni++)
                    hacc[ni] = __builtin_amdgcn_mfma_f32_16x16x32_bf16(h, bfr[ni], hacc[ni], 0, 0, 0);
            }
        }
        if (kt + 1 < nK) {
            int k0 = (kt + 1) << 6;
            if (haloLane) {   // global->VGPR, no LDS hazard: overlap with barrier
                hn0 = *(const bf16x8*)(A + (size_t)(m0 - 3 + lr) * K + k0 + lg * 8);
                hn1 = *(const bf16x8*)(A + (size_t)(m0 - 3 + lr) * K + k0 + 32 + lg * 8);
            }
            __syncthreads();   // all reads of tile kt retired
            #pragma unroll
            for (int j = 0; j < 2; j++) {
                int row = wave * 16 + j * 8 + slo;
                gload16(A + (size_t)(m0 + row) * K + k0 + skb, SM + (wave * 2 + j) * 512);
                gload16(B + (size_t)(n0 + row) * K + k0 + skb, SM + 8192 + (wave * 2 + j) * 512);
            }
            __syncthreads();   // drains vmcnt: tile kt+1 ready
            hc0 = hn0; hc1 = hn1;
        }
    }

    if (isXBC) {
        // ---- fused causal conv(k=4) + SiLU, sliding-window epilogue ----
        short* Tile = SM;   // [131][TS]: rows 0-2 = halo, 3+row = token m0+row
        __syncthreads();    // last tile's ds_reads done before aliasing
        #pragma unroll
        for (int mi = 0; mi < 2; mi++)
            #pragma unroll
            for (int ni = 0; ni < 4; ni++)
                #pragma unroll
                for (int r = 0; r < 4; r++) {
                    int row = wm * 32 + mi * 16 + lg * 4 + r;
                    int col = wn * 64 + ni * 16 + lr;
                    float v = acc[mi][ni][r];
                    float vo = __shfl_xor(v, 1);
                    if (!(lr & 1))
                        *(unsigned*)&Tile[(3 + row) * TS + col] = cvtpk(v, vo);
                }
        if (wm == 0 && lg == 0) {
            #pragma unroll
            for (int ni = 0; ni < 4; ni++)
                #pragma unroll
                for (int r = 0; r < 3; r++)
                    Tile[r * TS + wn * 64 + ni * 16 + lr] = (short)f2bf(hacc[ni][r]);
        }
        __syncthreads();
        int cp = tid & 63, rg = tid >> 6;   // 64 col-pairs x 8 row groups of 16
        int colb = cp * 2;
        int ch = (n0 - 512) + colb;
        float c0w0 = cw[ch * 4], c0w1 = cw[ch * 4 + 1], c0w2 = cw[ch * 4 + 2], c0w3 = cw[ch * 4 + 3];
        float c1w0 = cw[ch * 4 + 4], c1w1 = cw[ch * 4 + 5], c1w2 = cw[ch * 4 + 6], c1w3 = cw[ch * 4 + 7];
        float b0v = cb[ch], b1v = cb[ch + 1];
        int rbase = rg * 16;
        unsigned w0 = *(const unsigned*)&Tile[(rbase + 0) * TS + colb];
        unsigned w1 = *(const unsigned*)&Tile[(rbase + 1) * TS + colb];
        unsigned w2 = *(const unsigned*)&Tile[(rbase + 2) * TS + colb];
        for (int i = 0; i < 16; i++) {
            unsigned w3 = *(const unsigned*)&Tile[(rbase + i + 3) * TS + colb];
            float s0 = b0v, s1 = b1v;
            s0 = fmaf(bf2f((short)(w0 & 0xffffu)), c0w0, s0); s1 = fmaf(bf2f((short)(w0 >> 16)), c1w0, s1);
            s0 = fmaf(bf2f((short)(w1 & 0xffffu)), c0w1, s0); s1 = fmaf(bf2f((short)(w1 >> 16)), c1w1, s1);
            s0 = fmaf(bf2f((short)(w2 & 0xffffu)), c0w2, s0); s1 = fmaf(bf2f((short)(w2 >> 16)), c1w2, s1);
            s0 = fmaf(bf2f((short)(w3 & 0xffffu)), c0w3, s0); s1 = fmaf(bf2f((short)(w3 >> 16)), c1w3, s1);
            s0 = fsilu(s0);
            s1 = fsilu(s1);
            *(unsigned*)&xbc[(size_t)(m0 + rbase + i) * CONVD + ch] = cvtpk(s0, s1);
            w0 = w1; w1 = w2; w2 = w3;
        }
        return;
    }

    #pragma unroll
    for (int mi = 0; mi < 2; mi++) {
        #pragma unroll
        for (int r = 0; r < 4; r++) {
            int row = m0 + wm * 32 + mi * 16 + lg * 4 + r;
            #pragma unroll
            for (int ni = 0; ni < 4; ni++) {
                int col = n0 + wn * 64 + ni * 16 + lr;
                float v = acc[mi][ni][r];
                if (MODE == 0) {
                    float vo = __shfl_xor(v, 1);
                    if (!(lr & 1))
                        *(unsigned*)&z16[(size_t)row * DINNER + col] = cvtpk(v, vo);
                } else {
                    outF[(size_t)row * VOCAB + col] = v;
                }
            }
        }
    }
}

// ---------------- k_outproj: xf16 = bf16( rms(g)[m] * (g @ Wo'^T) + embed[ids] ) ----------------
__global__ __launch_bounds__(512) void k_outproj(
    const short* __restrict__ Y16, const short* __restrict__ z16,
    const short* __restrict__ Wo, const int* __restrict__ ids,
    const float* __restrict__ embed, short* __restrict__ xf16) {
    __shared__ __align__(16) short As[8192];
    __shared__ __align__(16) short Bs[8192];
    __shared__ float rmsS[128];
    int tid = threadIdx.x;
    int bid = blockIdx.x;                 // 512 blocks: 8 xcd x 32 m x 2 n
    int slot = bid >> 3;
    int m0 = (((bid & 7) * 32) + (slot >> 1)) << 7;
    int n0 = (slot & 1) << 7;
    int wave = tid >> 6, lane = tid & 63;
    int wm = wave >> 1, wn = wave & 1;
    int lr = lane & 15, lg = lane >> 4;
    const f32x4 zer = {0.f, 0.f, 0.f, 0.f};
    f32x4 acc[2][4];
    #pragma unroll
    for (int i = 0; i < 2; i++)
        #pragma unroll
        for (int j = 0; j < 4; j++) acc[i][j] = zer;

    const int arow = tid >> 2;            // A staging: row 0..127
    const int ac0 = (tid & 3) * 2;        // two 8-short chunks per thread
    const int slo = lane >> 3;
    const int skb = ((lane & 7) ^ slo) << 3;
    float ssq = 0.f;

    for (int kt = 0; kt < 8; ++kt) {
        int k0 = kt << 6;
        #pragma unroll
        for (int j = 0; j < 2; j++) {
            int row = wave * 16 + j * 8 + slo;
            gload16(Wo + (size_t)(n0 + row) * DINNER + k0 + skb, Bs + (wave * 2 + j) * 512);
        }
        union { int4 v; short s[8]; } y0u, y1u, z0u, z1u;
        const size_t rbase = (size_t)(m0 + arow) * DINNER + k0 + ac0 * 8;
        y0u.v = *(const int4*)(Y16 + rbase);
        y1u.v = *(const int4*)(Y16 + rbase + 8);
        z0u.v = *(const int4*)(z16 + rbase);
        z1u.v = *(const int4*)(z16 + rbase + 8);
        unsigned pk[8];
        #pragma unroll
        for (int e = 0; e < 4; e++) {
            float g0 = bf2f(y0u.s[2*e])     * fsilu(bf2f(z0u.s[2*e]));
            float g1 = bf2f(y0u.s[2*e + 1]) * fsilu(bf2f(z0u.s[2*e + 1]));
            ssq += g0 * g0 + g1 * g1;
            pk[e] = cvtpk(g0, g1);
        }
        #pragma unroll
        for (int e = 0; e < 4; e++) {
            float g0 = bf2f(y1u.s[2*e])     * fsilu(bf2f(z1u.s[2*e]));
            float g1 = bf2f(y1u.s[2*e + 1]) * fsilu(bf2f(z1u.s[2*e + 1]));
            ssq += g0 * g0 + g1 * g1;
            pk[4 + e] = cvtpk(g0, g1);
        }
        *(int4*)&As[arow * 64 + ((ac0 ^ (arow & 7)) << 3)] = *(int4*)&pk[0];
        *(int4*)&As[arow * 64 + (((ac0 + 1) ^ (arow & 7)) << 3)] = *(int4*)&pk[4];
        __syncthreads();   // drains gload vmcnt + ds_writes: tile kt ready
        #pragma unroll
        for (int kk = 0; kk < 2; kk++) {
            int sw = (((kk << 2) + lg) ^ (lr & 7)) << 3;
            bf16x8 af[2], bfr[4];
            #pragma unroll
            for (int mi = 0; mi < 2; mi++)
                af[mi] = *(const bf16x8*)&As[(wm * 32 + mi * 16 + lr) * 64 + sw];
            #pragma unroll
            for (int ni = 0; ni < 4; ni++)
                bfr[ni] = *(const bf16x8*)&Bs[(wn * 64 + ni * 16 + lr) * 64 + sw];
            #pragma unroll
            for (int mi = 0; mi < 2; mi++)
                #pragma unroll
                for (int ni = 0; ni < 4; ni++)
                    acc[mi][ni] = __builtin_amdgcn_mfma_f32_16x16x32_bf16(af[mi], bfr[ni], acc[mi][ni], 0, 0, 0);
        }
        __syncthreads();   // all reads done before next overwrite
    }
    ssq += __shfl_xor(ssq, 1);
    ssq += __shfl_xor(ssq, 2);
    if ((tid & 3) == 0) rmsS[arow] = rsqrtf(ssq * (1.0f / DINNER) + 1e-5f);
    __syncthreads();

    #pragma unroll
    for (int mi = 0; mi < 2; mi++) {
        #pragma unroll
        for (int r = 0; r < 4; r++) {
            int rl = wm * 32 + mi * 16 + lg * 4 + r;
            int row = m0 + rl;
            int id = ids[row];
            float rm = rmsS[rl];
            #pragma unroll
            for (int ni = 0; ni < 4; ni++) {
                int col = n0 + wn * 64 + ni * 16 + lr;
                float v = acc[mi][ni][r] * rm;
                float vo = __shfl_xor(v, 1);
                if (!(lr & 1)) {
                    float2 res = *(const float2*)&embed[(size_t)id * DMODEL + col];
                    *(unsigned*)&xf16[(size_t)row * DMODEL + col] = cvtpk(v + res.x, vo + res.y);
                }
            }
        }
    }
}

// ---------------- k_states: per (b,c,hg): chunk states, bulk-staged x, swizzled st16 write ----------------
__global__ __launch_bounds__(256) void k_states(const short* __restrict__ xbc, const float* __restrict__ dts,
                                                const float* __restrict__ A_log,
                                                short* __restrict__ st16,
                                                float* __restrict__ acs_g, float* __restrict__ cdec) {
    __shared__ short BsB[64 * 72];   // B[k][n]
    __shared__ short BT[64 * 72];    // B^T[n][k], built once
    __shared__ short XdS[32 * 72];   // Xd[p][k] per head (padded, MFMA operand)
    __shared__ __align__(16) short XKP[64 * 32];  // raw x tile [k][p], gload16 target
    __shared__ float dkS[HGRP][64];
    __shared__ float dtS[64];
    int tid = threadIdx.x;
    int bid = blockIdx.x;
    int hg = bid & 3;
    int bc = bid >> 2;
    int b = bc >> 6, c = bc & 63;
    int h0 = hg * HGRP;
    size_t tbase = (size_t)b * SEQ + (size_t)c * 64;
    int wave = tid >> 6, lane = tid & 63;
    int lr = lane & 15, lg = lane >> 4;

    for (int i = tid; i < 64 * 64; i += 256) {
        int q = i >> 6, n = i & 63;
        BsB[q * 72 + n] = xbc[(tbase + q) * CONVD + DINNER + n];
    }
    {
        int h = h0 + wave;
        float Ah = -__expf(A_log[h]);
        float v = dts[(tbase + lane) * NH + h] * Ah;
        #pragma unroll
        for (int off = 1; off < 64; off <<= 1) {
            float o = __shfl_up(v, off);
            if (lane >= off) v += o;
        }
        acs_g[(((size_t)(b * NH + h)) * 64 + c) * 64 + lane] = v;
        float alast = __shfl(v, 63);
        dkS[wave][lane] = __expf(alast - v);
        if (lane == 0) cdec[(b * NH + h) * 64 + c] = __expf(alast);
    }
    __syncthreads();
    for (int i = tid; i < 64 * 64; i += 256) {
        int k = i >> 6, n = i & 63;
        BT[n * 72 + k] = BsB[k * 72 + n];
    }

    for (int hh = 0; hh < HGRP; hh++) {
        int h = h0 + hh;
        {
            int s = wave * 64 + lane;
            gload16(xbc + (tbase + (s >> 2)) * CONVD + h * HD + (s & 3) * 8, XKP + wave * 512);
        }
        if (tid < 64) dtS[tid] = dts[(tbase + tid) * NH + h];
        __syncthreads();
        for (int i = tid; i < 2048; i += 256) {
            int p = i & 31, k = i >> 5;
            XdS[p * 72 + k] = (short)f2bf(bf2f(XKP[k * 32 + p]) * dtS[k] * dkS[hh][k]);
        }
        __syncthreads();
        {
            int ptile = wave & 1;
            bf16x8 a0 = *(const bf16x8*)&XdS[(ptile * 16 + lr) * 72 + lg * 8];
            bf16x8 a1 = *(const bf16x8*)&XdS[(ptile * 16 + lr) * 72 + 32 + lg * 8];
            size_t base = ((size_t)bc * NH + h) * 2048;
            #pragma unroll
            for (int j = 0; j < 2; j++) {
                int nt = (wave >> 1) * 2 + j;
                bf16x8 b0 = *(const bf16x8*)&BT[(nt * 16 + lr) * 72 + lg * 8];
                bf16x8 b1 = *(const bf16x8*)&BT[(nt * 16 + lr) * 72 + 32 + lg * 8];
                f32x4 z = {0.f, 0.f, 0.f, 0.f};
                z = __builtin_amdgcn_mfma_f32_16x16x32_bf16(a0, b0, z, 0, 0, 0);
                z = __builtin_amdgcn_mfma_f32_16x16x32_bf16(a1, b1, z, 0, 0, 0);
                #pragma unroll
                for (int r = 0; r < 4; r++) {
                    int p = ptile * 16 + lg * 4 + r;
                    float v = z[r];
                    float vo = __shfl_xor(v, 1);
                    if (!(lr & 1)) {
                        int chunk = (nt << 1) | (lr >> 3);
                        *(unsigned*)&st16[base + p * 64 + ((chunk ^ (p & 7)) << 3) + (lr & 7)] = cvtpk(v, vo);
                    }
                }
            }
        }
        __syncthreads();
    }
}

// ---------------- k_scan: sequential inter-chunk scan on bf16 states (fp32 accum) ----------------
__global__ __launch_bounds__(256) void k_scan(unsigned* __restrict__ st32, const float* __restrict__ cdec) {
    int bid = blockIdx.x;           // BATCH*NH*4
    int bh = bid >> 2, seg = bid & 3;
    int b = bh >> 4, h = bh & 15;
    int off = seg * 256 + threadIdx.x;   // u32 index within 1024
    float p0 = 0.f, p1 = 0.f;
    for (int c = 0; c < 64; c++) {
        float dec = cdec[bh * 64 + c];
        size_t idx = ((((size_t)b * 64 + c) * NH) + h) * 1024 + off;
        unsigned v = st32[idx];
        float s0 = bf2f((short)(v & 0xffffu));
        float s1 = bf2f((short)(v >> 16));
        st32[idx] = cvtpk(p0, p1);
        p0 = fmaf(dec, p0, s0);
        p1 = fmaf(dec, p1, s1);
    }
}

// ---------------- k_y: Y16 = Y_diag + exp(acs)*(C . prev^T) + D*x ----------------
__global__ __launch_bounds__(256) void k_y(const short* __restrict__ xbc, const float* __restrict__ dts,
                                           const short* __restrict__ st16, const float* __restrict__ acs_g,
                                           const float* __restrict__ D_skip, short* __restrict__ Y16) {
    __shared__ short CsB[64 * 72];   // C[q][n], live throughout
    __shared__ short Wsh[64 * 72];   // B at load; W per head after M
    __shared__ short XtS[32 * 72];   // Xt[p][k] per head (padded, MFMA operand)
    __shared__ __align__(16) short PtL[32 * 64];  // prev tile, linear copy of (swizzled) st16
    __shared__ __align__(16) short XKP[64 * 32];  // raw x tile [k][p]
    __shared__ float acsH[64];
    __shared__ float dtS[64];
    int tid = threadIdx.x;
    int bid = blockIdx.x;
    int hg = bid & 3;
    int bc = bid >> 2;
    int b = bc >> 6, c = bc & 63;
    int h0 = hg * HGRP;
    size_t tbase = (size_t)b * SEQ + (size_t)c * 64;
    int wave = tid >> 6, lane = tid & 63;
    int lr = lane & 15, lg = lane >> 4;

    for (int i = tid; i < 64 * 64; i += 256) {
        int q = i >> 6, n = i & 63;
        const short* rowp = xbc + (tbase + q) * CONVD + DINNER;
        Wsh[q * 72 + n] = rowp[n];            // B (consumed by M, then reused as W)
        CsB[q * 72 + n] = rowp[DSTATE + n];   // C
    }
    __syncthreads();

    // M = C . B^T : wave owns q-strip of 16 rows, kept in regs
    f32x4 macc[4];
    bf16x8 ca0 = *(const bf16x8*)&CsB[(wave * 16 + lr) * 72 + lg * 8];
    bf16x8 ca1 = *(const bf16x8*)&CsB[(wave * 16 + lr) * 72 + 32 + lg * 8];
    {
        #pragma unroll
        for (int ct = 0; ct < 4; ct++) {
            bf16x8 b0 = *(const bf16x8*)&Wsh[(ct * 16 + lr) * 72 + lg * 8];
            bf16x8 b1 = *(const bf16x8*)&Wsh[(ct * 16 + lr) * 72 + 32 + lg * 8];
            f32x4 z = {0.f, 0.f, 0.f, 0.f};
            z = __builtin_amdgcn_mfma_f32_16x16x32_bf16(ca0, b0, z, 0, 0, 0);
            z = __builtin_amdgcn_mfma_f32_16x16x32_bf16(ca1, b1, z, 0, 0, 0);
            macc[ct] = z;
        }
    }
    __syncthreads();   // all waves done reading B before Wsh is overwritten

    for (int hh = 0; hh < HGRP; hh++) {
        int h = h0 + hh;
        // phase 1: issue bulk loads + stage per-head scalars
        {
            int s = wave * 64 + lane;
            gload16(xbc + (tbase + (s >> 2)) * CONVD + h * HD + (s & 3) * 8, XKP + wave * 512);
            gload16(st16 + ((size_t)bc * NH + h) * 2048 + s * 8, PtL + wave * 512);
        }
        if (tid < 64) {
            acsH[tid] = acs_g[(((size_t)(b * NH + h)) * 64 + c) * 64 + tid];
            dtS[tid] = dts[(tbase + tid) * NH + h];
        }
        __syncthreads();
        // phase 2: W build (wave-local rows) + Xt transpose
        #pragma unroll
        for (int ct = 0; ct < 4; ct++) {
            int k = ct * 16 + lr;
            #pragma unroll
            for (int r = 0; r < 4; r++) {
                int q = wave * 16 + lg * 4 + r;
                float wv = 0.f;
                if (k <= q) wv = macc[ct][r] * __expf(acsH[q] - acsH[k]);
                float wo = __shfl_xor(wv, 1);
                if (!(lr & 1))
                    *(unsigned*)&Wsh[q * 72 + k] = cvtpk(wv, wo);
            }
        }
        for (int i = tid; i < 2048; i += 256) {
            int p = i & 31, k = i >> 5;
            XtS[p * 72 + k] = (short)f2bf(bf2f(XKP[k * 32 + p]) * dtS[k]);
        }
        __syncthreads();
        // phase 3: MFMAs + Y write
        float eq[4];
        #pragma unroll
        for (int r = 0; r < 4; r++) eq[r] = __expf(acsH[wave * 16 + lg * 4 + r]);
        float dsk = D_skip[h];
        bf16x8 wa0 = *(const bf16x8*)&Wsh[(wave * 16 + lr) * 72 + lg * 8];
        bf16x8 wa1 = *(const bf16x8*)&Wsh[(wave * 16 + lr) * 72 + 32 + lg * 8];
        #pragma unroll
        for (int pt = 0; pt < 2; pt++) {
            int p = pt * 16 + lr;
            bf16x8 xb0 = *(const bf16x8*)&XtS[p * 72 + lg * 8];
            bf16x8 xb1 = *(const bf16x8*)&XtS[p * 72 + 32 + lg * 8];
            f32x4 zd = {0.f, 0.f, 0.f, 0.f};
            zd = __builtin_amdgcn_mfma_f32_16x16x32_bf16(wa0, xb0, zd, 0, 0, 0);
            zd = __builtin_amdgcn_mfma_f32_16x16x32_bf16(wa1, xb1, zd, 0, 0, 0);
            bf16x8 pb0 = *(const bf16x8*)&PtL[p * 64 + ((lg ^ (p & 7)) << 3)];
            bf16x8 pb1 = *(const bf16x8*)&PtL[p * 64 + (((lg + 4) ^ (p & 7)) << 3)];
            f32x4 zo = {0.f, 0.f, 0.f, 0.f};
            zo = __builtin_amdgcn_mfma_f32_16x16x32_bf16(ca0, pb0, zo, 0, 0, 0);
            zo = __builtin_amdgcn_mfma_f32_16x16x32_bf16(ca1, pb1, zo, 0, 0, 0);
            #pragma unroll
            for (int r = 0; r < 4; r++) {
                int q = wave * 16 + lg * 4 + r;
                float xv = bf2f(XKP[q * 32 + p]);
                float v = zd[r] + eq[r] * zo[r] + dsk * xv;
                float vo = __shfl_xor(v, 1);
                if (!(lr & 1))
                    *(unsigned*)&Y16[((tbase + q) * NH + h) * HD + p] = cvtpk(v, vo);
            }
        }
        __syncthreads();   // protect buffers before next head overwrite
    }
}

extern "C" void kernel_launch(void* const* d_in, const int* in_sizes, int n_in,
                              void* d_out, int out_size, void* d_ws, size_t ws_size,
                              hipStream_t stream) {
    const int*   ids        = (const int*)d_in[0];
    const float* embed_w    = (const float*)d_in[1];
    const float* in_proj_w  = (const float*)d_in[2];
    const float* conv_w     = (const float*)d_in[3];
    const float* conv_b     = (const float*)d_in[4];
    const float* A_log      = (const float*)d_in[5];
    const float* D_skip     = (const float*)d_in[6];
    const float* dt_bias    = (const float*)d_in[7];
    const float* gate_w     = (const float*)d_in[8];
    const float* out_proj_w = (const float*)d_in[9];
    const float* norm_w     = (const float*)d_in[10];
    float* out = (float*)d_out;

    if (ws_size < WS_FLOATS * sizeof(float)) {
        k_diag<<<1, 64, 0, stream>>>(out, (float)(ws_size >> 20));
        return;
    }

    float* ws   = (float*)d_ws;
    short* u16  = (short*)(ws + U16_OFF);
    short* z16  = (short*)(ws + Z16_OFF);
    short* xbc  = (short*)(ws + XBC_OFF);
    float* dts  = ws + DTS_OFF;
    float* acs  = ws + ACS_OFF;
    float* cdec = ws + CDEC_OFF;
    short* Wp   = (short*)(ws + WP_OFF);
    short* Wo   = (short*)(ws + WO_OFF);
    short* We   = (short*)(ws + WE_OFF);
    short* st16 = (short*)(ws + UNION_OFF);                 // bf16 states (swizzled)
    short* Y16  = (short*)(ws + UNION_OFF + Y16_SUB);       // bf16 Y (live through k_outproj)
    short* xf16 = (short*)(ws + UNION_OFF);                 // aliases dead st16

    k_cvt<<<(NPAD * DMODEL + 255) / 256, 256, 0, stream>>>(in_proj_w, Wp, NPAD * DMODEL, NPAD * DMODEL);
    k_cvt_gate<<<(DMODEL * DINNER + 255) / 256, 256, 0, stream>>>(out_proj_w, gate_w, Wo, DMODEL * DINNER);
    k_cvt<<<(VOCAB * DMODEL + 255) / 256, 256, 0, stream>>>(embed_w, We, VOCAB * DMODEL, VOCAB * DMODEL);
    k_embed<<<TOK, 64, 0, stream>>>(ids, embed_w, norm_w, in_proj_w, dt_bias, u16, dts);
    k_gemm_mfma<0><<<(NPAD / 128) * 256, 512, 0, stream>>>(
        u16, Wp, DMODEL, nullptr, z16, xbc, conv_w, conv_b);
    k_states<<<BATCH * 64 * 4, 256, 0, stream>>>(xbc, dts, A_log, st16, acs, cdec);
    k_scan<<<BATCH * NH * 4, 256, 0, stream>>>((unsigned*)st16, cdec);
    k_y<<<BATCH * 64 * 4, 256, 0, stream>>>(xbc, dts, st16, acs, D_skip, Y16);
    k_outproj<<<(DMODEL / 128) * 256, 512, 0, stream>>>(Y16, z16, Wo, ids, embed_w, xf16);
    k_gemm_mfma<2><<<(VOCAB / 128) * 256, 512, 0, stream>>>(
        xf16, We, DMODEL, out, nullptr, nullptr, nullptr, nullptr);
}

// Round 21
// 215.597 us; speedup vs baseline: 1.2234x; 1.2234x over previous
//
#include <hip/hip_runtime.h>
#include <cstdint>
#include <cstddef>

#define TOK    32768   // B*L
#define BATCH  8
#define SEQ    4096
#define DMODEL 256
#define DINNER 512
#define DSTATE 64
#define NH     16
#define HD     32
#define DPROJ  1168
#define NPAD   1280    // in_proj N padded to 10*128
#define CONVD  640
#define VOCAB  512
#define HGRP   4       // heads per states/y block
#define TS     132     // conv tile LDS stride (shorts)

typedef __attribute__((ext_vector_type(8))) short bf16x8;
typedef __attribute__((ext_vector_type(4))) float f32x4;

__device__ __forceinline__ unsigned short f2bf(float f) {
    unsigned u = __float_as_uint(f);
    u += 0x7fffu + ((u >> 16) & 1u);       // RNE
    return (unsigned short)(u >> 16);
}
__device__ __forceinline__ float bf2f(short s) {
    return __uint_as_float(((unsigned)(unsigned short)s) << 16);
}
// pack two f32 -> two bf16 (RNE) in one instruction
__device__ __forceinline__ unsigned cvtpk(float lo, float hi) {
    unsigned r;
    asm("v_cvt_pk_bf16_f32 %0, %1, %2" : "=v"(r) : "v"(lo), "v"(hi));
    return r;
}
__device__ __forceinline__ float fsilu(float s) {
    return s * __builtin_amdgcn_rcpf(1.f + __expf(-s));
}
__device__ __forceinline__ float sp(float v) {
    return v > 20.f ? v : __logf(1.f + __expf(v));
}

// async global->LDS, 16B per lane; dst wave-uniform base, lane fills dst+lane*16B
__device__ __forceinline__ void gload16(const short* src, short* dst) {
    __builtin_amdgcn_global_load_lds((const __attribute__((address_space(1))) void*)src,
                                     (__attribute__((address_space(3))) void*)dst, 16, 0, 0);
}

// ---------------- ws layout (floats, all 16B aligned) ----------------
#define U16_OFF   0                                    // TOK*256 bf16
#define Z16_OFF   (U16_OFF  + (size_t)TOK*128)         // TOK*512 bf16
#define XBC_OFF   (Z16_OFF  + (size_t)TOK*256)         // TOK*640 bf16
#define DTS_OFF   (XBC_OFF  + (size_t)TOK*320)         // TOK*16 fp32
#define ACS_OFF   (DTS_OFF  + (size_t)TOK*16)
#define CDEC_OFF  (ACS_OFF  + (size_t)BATCH*NH*64*64)
#define WP_OFF    (CDEC_OFF + (size_t)BATCH*NH*64)
#define WO_OFF    (WP_OFF   + 163840)
#define WE_OFF    (WO_OFF   + 65536)
#define UNION_OFF (WE_OFF   + 65536)
// union: [0,TOK*256): st16 bf16 (dead after k_y) -> xf16 bf16
//        [TOK*256,TOK*512): Y16 bf16 (read by k_outproj)
#define UNION_FL  ((size_t)BATCH*64*NH*2048)
#define Y16_SUB   ((size_t)TOK*256)
#define WS_FLOATS (UNION_OFF + UNION_FL)

__global__ void k_diag(float* out, float wsmb) {
    if (blockIdx.x == 0 && threadIdx.x == 0) out[0] = wsmb;
}

// ---------------- weight fp32 -> bf16 (+ zero pad) ----------------
__global__ void k_cvt(const float* __restrict__ s, short* __restrict__ d, int nsrc, int ntot) {
    int i = blockIdx.x * 256 + threadIdx.x;
    if (i < ntot) d[i] = (i < nsrc) ? (short)f2bf(s[i]) : (short)0;
}
// Wo' = Wo * gate_norm_w (folded gate weight; K = DINNER, power of 2)
__global__ void k_cvt_gate(const float* __restrict__ s, const float* __restrict__ gw,
                           short* __restrict__ d, int ntot) {
    int i = blockIdx.x * 256 + threadIdx.x;
    if (i < ntot) d[i] = (short)f2bf(s[i] * gw[i & (DINNER - 1)]);
}

// ---------------- embed gather + rmsnorm -> u16 (bf16) ----------------
__global__ void k_embed(const int* __restrict__ ids, const float* __restrict__ embed,
                        const float* __restrict__ norm_w, short* __restrict__ u16) {
    int t = blockIdx.x;
    int lane = threadIdx.x;   // 64
    int id = ids[t];
    float4 v = ((const float4*)(embed + (size_t)id * DMODEL))[lane];
    float ss = v.x*v.x + v.y*v.y + v.z*v.z + v.w*v.w;
    #pragma unroll
    for (int o = 32; o > 0; o >>= 1) ss += __shfl_down(ss, o);
    ss = __shfl(ss, 0);
    float r = rsqrtf(ss * (1.0f / DMODEL) + 1e-6f);
    float4 w = ((const float4*)norm_w)[lane];
    unsigned p0 = cvtpk(v.x * r * w.x, v.y * r * w.y);
    unsigned p1 = cvtpk(v.z * r * w.z, v.w * r * w.w);
    ((uint2*)(u16 + (size_t)t * DMODEL))[lane] = make_uint2(p0, p1);
}

// ---------------- bf16 MFMA GEMM: 512 threads (8 waves), 128x128 tile, BK=64 ----------------
// Single 32KB LDS buffer, two barriers/iter; rule-#21 swizzle; XCD-aware tile map (T1).
// MODE 0: in_proj (z16 / conv+silu->xbc / dt).  MODE 2: logits fp32.
template<int MODE>
__global__ __launch_bounds__(512) void k_gemm_mfma(
    const short* __restrict__ A, const short* __restrict__ B, int K,
    float* __restrict__ outF, short* __restrict__ z16, short* __restrict__ xbc,
    float* __restrict__ dts, const float* __restrict__ dt_bias,
    const float* __restrict__ cw, const float* __restrict__ cb) {
    // A (8192 shorts) | B (8192 shorts); MODE 0 conv Tile aliases (131*TS = 17292)
    __shared__ __align__(16) short SM[MODE == 0 ? (131 * TS) : 16384];
    constexpr int NX = (MODE == 0) ? (NPAD / 128) : (VOCAB / 128);
    int tid = threadIdx.x;
    int bid = blockIdx.x;
    int slot = bid >> 3;
    int m0 = (((bid & 7) * 32) + slot / NX) << 7;
    int n0 = (slot % NX) << 7;
    int wave = tid >> 6, lane = tid & 63;
    int wm = wave >> 1, wn = wave & 1;
    int lr = lane & 15, lg = lane >> 4;
    const f32x4 zer = {0.f, 0.f, 0.f, 0.f};
    f32x4 acc[2][4];
    #pragma unroll
    for (int i = 0; i < 2; i++)
        #pragma unroll
        for (int j = 0; j < 4; j++) acc[i][j] = zer;

    const bool isXBC = (MODE == 0) && (n0 >= 512) && (n0 < 1152);
    const bool atStart = (m0 & (SEQ - 1)) == 0;
    const bool haloLane = isXBC && (wm == 0) && !atStart && (lr < 3);
    f32x4 hacc[4];
    #pragma unroll
    for (int j = 0; j < 4; j++) hacc[j] = zer;
    const bf16x8 hz = {0, 0, 0, 0, 0, 0, 0, 0};
    bf16x8 hc0 = hz, hc1 = hz, hn0 = hz, hn1 = hz;

    const int nK = K >> 6;
    const int slo = lane >> 3;
    const int skb = ((lane & 7) ^ slo) << 3;

    // prologue: stage tile 0 (+halo regs)
    {
        #pragma unroll
        for (int j = 0; j < 2; j++) {
            int row = wave * 16 + j * 8 + slo;
            gload16(A + (size_t)(m0 + row) * K + skb, SM + (wave * 2 + j) * 512);
            gload16(B + (size_t)(n0 + row) * K + skb, SM + 8192 + (wave * 2 + j) * 512);
        }
        if (haloLane) {
            hc0 = *(const bf16x8*)(A + (size_t)(m0 - 3 + lr) * K + lg * 8);
            hc1 = *(const bf16x8*)(A + (size_t)(m0 - 3 + lr) * K + 32 + lg * 8);
        }
    }
    __syncthreads();   // drains vmcnt: tile 0 ready

    for (int kt = 0; kt < nK; ++kt) {
        #pragma unroll
        for (int kk = 0; kk < 2; kk++) {
            int sw = (((kk << 2) + lg) ^ (lr & 7)) << 3;
            bf16x8 af[2], bfr[4];
            #pragma unroll
            for (int mi = 0; mi < 2; mi++)
                af[mi] = *(const bf16x8*)&SM[(wm * 32 + mi * 16 + lr) * 64 + sw];
            #pragma unroll
            for (int ni = 0; ni < 4; ni++)
                bfr[ni] = *(const bf16x8*)&SM[8192 + (wn * 64 + ni * 16 + lr) * 64 + sw];
            #pragma unroll
            for (int mi = 0; mi < 2; mi++)
                #pragma unroll
                for (int ni = 0; ni < 4; ni++)
                    acc[mi][ni] = __builtin_amdgcn_mfma_f32_16x16x32_bf16(af[mi], bfr[ni], acc[mi][ni], 0, 0, 0);
            if (isXBC && wm == 0) {
                bf16x8 h = (kk == 0) ? hc0 : hc1;
                #pragma unroll
                for (int ni = 0; ni < 4; ni++)
                    hacc[ni] = __builtin_amdgcn_mfma_f32_16x16x32_bf16(h, bfr[ni], hacc[ni], 0, 0, 0);
            }
        }
        if (kt + 1 < nK) {
            int k0 = (kt + 1) << 6;
            if (haloLane) {   // global->VGPR, no LDS hazard: overlap with barrier
                hn0 = *(const bf16x8*)(A + (size_t)(m0 - 3 + lr) * K + k0 + lg * 8);
                hn1 = *(const bf16x8*)(A + (size_t)(m0 - 3 + lr) * K + k0 + 32 + lg * 8);
            }
            __syncthreads();   // all reads of tile kt retired
            #pragma unroll
            for (int j = 0; j < 2; j++) {
                int row = wave * 16 + j * 8 + slo;
                gload16(A + (size_t)(m0 + row) * K + k0 + skb, SM + (wave * 2 + j) * 512);
                gload16(B + (size_t)(n0 + row) * K + k0 + skb, SM + 8192 + (wave * 2 + j) * 512);
            }
            __syncthreads();   // drains vmcnt: tile kt+1 ready
            hc0 = hn0; hc1 = hn1;
        }
    }

    if (isXBC) {
        // ---- fused causal conv(k=4) + SiLU, sliding-window epilogue ----
        short* Tile = SM;   // [131][TS]: rows 0-2 = halo, 3+row = token m0+row
        __syncthreads();    // last tile's ds_reads done before aliasing
        #pragma unroll
        for (int mi = 0; mi < 2; mi++)
            #pragma unroll
            for (int ni = 0; ni < 4; ni++)
                #pragma unroll
                for (int r = 0; r < 4; r++) {
                    int row = wm * 32 + mi * 16 + lg * 4 + r;
                    int col = wn * 64 + ni * 16 + lr;
                    float v = acc[mi][ni][r];
                    float vo = __shfl_xor(v, 1);
                    if (!(lr & 1))
                        *(unsigned*)&Tile[(3 + row) * TS + col] = cvtpk(v, vo);
                }
        if (wm == 0 && lg == 0) {
            #pragma unroll
            for (int ni = 0; ni < 4; ni++)
                #pragma unroll
                for (int r = 0; r < 3; r++)
                    Tile[r * TS + wn * 64 + ni * 16 + lr] = (short)f2bf(hacc[ni][r]);
        }
        __syncthreads();
        int cp = tid & 63, rg = tid >> 6;   // 64 col-pairs x 8 row groups of 16
        int colb = cp * 2;
        int ch = (n0 - 512) + colb;
        float c0w0 = cw[ch * 4], c0w1 = cw[ch * 4 + 1], c0w2 = cw[ch * 4 + 2], c0w3 = cw[ch * 4 + 3];
        float c1w0 = cw[ch * 4 + 4], c1w1 = cw[ch * 4 + 5], c1w2 = cw[ch * 4 + 6], c1w3 = cw[ch * 4 + 7];
        float b0v = cb[ch], b1v = cb[ch + 1];
        int rbase = rg * 16;
        unsigned w0 = *(const unsigned*)&Tile[(rbase + 0) * TS + colb];
        unsigned w1 = *(const unsigned*)&Tile[(rbase + 1) * TS + colb];
        unsigned w2 = *(const unsigned*)&Tile[(rbase + 2) * TS + colb];
        for (int i = 0; i < 16; i++) {
            unsigned w3 = *(const unsigned*)&Tile[(rbase + i + 3) * TS + colb];
            float s0 = b0v, s1 = b1v;
            s0 = fmaf(bf2f((short)(w0 & 0xffffu)), c0w0, s0); s1 = fmaf(bf2f((short)(w0 >> 16)), c1w0, s1);
            s0 = fmaf(bf2f((short)(w1 & 0xffffu)), c0w1, s0); s1 = fmaf(bf2f((short)(w1 >> 16)), c1w1, s1);
            s0 = fmaf(bf2f((short)(w2 & 0xffffu)), c0w2, s0); s1 = fmaf(bf2f((short)(w2 >> 16)), c1w2, s1);
            s0 = fmaf(bf2f((short)(w3 & 0xffffu)), c0w3, s0); s1 = fmaf(bf2f((short)(w3 >> 16)), c1w3, s1);
            s0 = fsilu(s0);
            s1 = fsilu(s1);
            *(unsigned*)&xbc[(size_t)(m0 + rbase + i) * CONVD + ch] = cvtpk(s0, s1);
            w0 = w1; w1 = w2; w2 = w3;
        }
        return;
    }

    #pragma unroll
    for (int mi = 0; mi < 2; mi++) {
        #pragma unroll
        for (int r = 0; r < 4; r++) {
            int row = m0 + wm * 32 + mi * 16 + lg * 4 + r;
            #pragma unroll
            for (int ni = 0; ni < 4; ni++) {
                int col = n0 + wn * 64 + ni * 16 + lr;
                float v = acc[mi][ni][r];
                if (MODE == 0) {
                    if (n0 < 512) {
                        float vo = __shfl_xor(v, 1);
                        if (!(lr & 1))
                            *(unsigned*)&z16[(size_t)row * DINNER + col] = cvtpk(v, vo);
                    } else if (wn == 0 && ni == 0) {
                        dts[(size_t)row * NH + lr] = sp(v + dt_bias[lr]);
                    }
                } else {
                    outF[(size_t)row * VOCAB + col] = v;
                }
            }
        }
    }
}

// ---------------- k_outproj: xf16 = bf16( rms(g)[m] * (g @ Wo'^T) + embed[ids] ) ----------------
__global__ __launch_bounds__(512) void k_outproj(
    const short* __restrict__ Y16, const short* __restrict__ z16,
    const short* __restrict__ Wo, const int* __restrict__ ids,
    const float* __restrict__ embed, short* __restrict__ xf16) {
    __shared__ __align__(16) short As[8192];
    __shared__ __align__(16) short Bs[8192];
    __shared__ float rmsS[128];
    int tid = threadIdx.x;
    int bid = blockIdx.x;                 // 512 blocks: 8 xcd x 32 m x 2 n
    int slot = bid >> 3;
    int m0 = (((bid & 7) * 32) + (slot >> 1)) << 7;
    int n0 = (slot & 1) << 7;
    int wave = tid >> 6, lane = tid & 63;
    int wm = wave >> 1, wn = wave & 1;
    int lr = lane & 15, lg = lane >> 4;
    const f32x4 zer = {0.f, 0.f, 0.f, 0.f};
    f32x4 acc[2][4];
    #pragma unroll
    for (int i = 0; i < 2; i++)
        #pragma unroll
        for (int j = 0; j < 4; j++) acc[i][j] = zer;

    const int arow = tid >> 2;            // A staging: row 0..127
    const int ac0 = (tid & 3) * 2;        // two 8-short chunks per thread
    const int slo = lane >> 3;
    const int skb = ((lane & 7) ^ slo) << 3;
    float ssq = 0.f;

    for (int kt = 0; kt < 8; ++kt) {
        int k0 = kt << 6;
        #pragma unroll
        for (int j = 0; j < 2; j++) {
            int row = wave * 16 + j * 8 + slo;
            gload16(Wo + (size_t)(n0 + row) * DINNER + k0 + skb, Bs + (wave * 2 + j) * 512);
        }
        union { int4 v; short s[8]; } y0u, y1u, z0u, z1u;
        const size_t rbase = (size_t)(m0 + arow) * DINNER + k0 + ac0 * 8;
        y0u.v = *(const int4*)(Y16 + rbase);
        y1u.v = *(const int4*)(Y16 + rbase + 8);
        z0u.v = *(const int4*)(z16 + rbase);
        z1u.v = *(const int4*)(z16 + rbase + 8);
        unsigned pk[8];
        #pragma unroll
        for (int e = 0; e < 4; e++) {
            float g0 = bf2f(y0u.s[2*e])     * fsilu(bf2f(z0u.s[2*e]));
            float g1 = bf2f(y0u.s[2*e + 1]) * fsilu(bf2f(z0u.s[2*e + 1]));
            ssq += g0 * g0 + g1 * g1;
            pk[e] = cvtpk(g0, g1);
        }
        #pragma unroll
        for (int e = 0; e < 4; e++) {
            float g0 = bf2f(y1u.s[2*e])     * fsilu(bf2f(z1u.s[2*e]));
            float g1 = bf2f(y1u.s[2*e + 1]) * fsilu(bf2f(z1u.s[2*e + 1]));
            ssq += g0 * g0 + g1 * g1;
            pk[4 + e] = cvtpk(g0, g1);
        }
        *(int4*)&As[arow * 64 + ((ac0 ^ (arow & 7)) << 3)] = *(int4*)&pk[0];
        *(int4*)&As[arow * 64 + (((ac0 + 1) ^ (arow & 7)) << 3)] = *(int4*)&pk[4];
        __syncthreads();   // drains gload vmcnt + ds_writes: tile kt ready
        #pragma unroll
        for (int kk = 0; kk < 2; kk++) {
            int sw = (((kk << 2) + lg) ^ (lr & 7)) << 3;
            bf16x8 af[2], bfr[4];
            #pragma unroll
            for (int mi = 0; mi < 2; mi++)
                af[mi] = *(const bf16x8*)&As[(wm * 32 + mi * 16 + lr) * 64 + sw];
            #pragma unroll
            for (int ni = 0; ni < 4; ni++)
                bfr[ni] = *(const bf16x8*)&Bs[(wn * 64 + ni * 16 + lr) * 64 + sw];
            #pragma unroll
            for (int mi = 0; mi < 2; mi++)
                #pragma unroll
                for (int ni = 0; ni < 4; ni++)
                    acc[mi][ni] = __builtin_amdgcn_mfma_f32_16x16x32_bf16(af[mi], bfr[ni], acc[mi][ni], 0, 0, 0);
        }
        __syncthreads();   // all reads done before next overwrite
    }
    // per-row rms: reduce sumsq across the 4 staging threads of each row
    ssq += __shfl_xor(ssq, 1);
    ssq += __shfl_xor(ssq, 2);
    if ((tid & 3) == 0) rmsS[arow] = rsqrtf(ssq * (1.0f / DINNER) + 1e-5f);
    __syncthreads();

    #pragma unroll
    for (int mi = 0; mi < 2; mi++) {
        #pragma unroll
        for (int r = 0; r < 4; r++) {
            int rl = wm * 32 + mi * 16 + lg * 4 + r;
            int row = m0 + rl;
            int id = ids[row];
            float rm = rmsS[rl];
            #pragma unroll
            for (int ni = 0; ni < 4; ni++) {
                int col = n0 + wn * 64 + ni * 16 + lr;
                float v = acc[mi][ni][r] * rm;
                float vo = __shfl_xor(v, 1);
                if (!(lr & 1)) {
                    float2 res = *(const float2*)&embed[(size_t)id * DMODEL + col];
                    *(unsigned*)&xf16[(size_t)row * DMODEL + col] = cvtpk(v + res.x, vo + res.y);
                }
            }
        }
    }
}

// ---------------- k_states: per (b,c,hg): chunk states, bulk-staged x, swizzled st16 write ----------------
__global__ __launch_bounds__(256) void k_states(const short* __restrict__ xbc, const float* __restrict__ dts,
                                                const float* __restrict__ A_log,
                                                short* __restrict__ st16,
                                                float* __restrict__ acs_g, float* __restrict__ cdec) {
    __shared__ short BsB[64 * 72];   // B[k][n]
    __shared__ short BT[64 * 72];    // B^T[n][k], built once
    __shared__ short XdS[32 * 72];   // Xd[p][k] per head (padded, MFMA operand)
    __shared__ __align__(16) short XKP[64 * 32];  // raw x tile [k][p], gload16 target
    __shared__ float dkS[HGRP][64];
    __shared__ float dtS[64];
    int tid = threadIdx.x;
    int bid = blockIdx.x;
    int hg = bid & 3;
    int bc = bid >> 2;
    int b = bc >> 6, c = bc & 63;
    int h0 = hg * HGRP;
    size_t tbase = (size_t)b * SEQ + (size_t)c * 64;
    int wave = tid >> 6, lane = tid & 63;
    int lr = lane & 15, lg = lane >> 4;

    for (int i = tid; i < 64 * 64; i += 256) {
        int q = i >> 6, n = i & 63;
        BsB[q * 72 + n] = xbc[(tbase + q) * CONVD + DINNER + n];
    }
    {
        int h = h0 + wave;
        float Ah = -__expf(A_log[h]);
        float v = dts[(tbase + lane) * NH + h] * Ah;
        #pragma unroll
        for (int off = 1; off < 64; off <<= 1) {
            float o = __shfl_up(v, off);
            if (lane >= off) v += o;
        }
        acs_g[(((size_t)(b * NH + h)) * 64 + c) * 64 + lane] = v;
        float alast = __shfl(v, 63);
        dkS[wave][lane] = __expf(alast - v);
        if (lane == 0) cdec[(b * NH + h) * 64 + c] = __expf(alast);
    }
    __syncthreads();
    for (int i = tid; i < 64 * 64; i += 256) {
        int k = i >> 6, n = i & 63;
        BT[n * 72 + k] = BsB[k * 72 + n];
    }

    for (int hh = 0; hh < HGRP; hh++) {
        int h = h0 + hh;
        {
            int s = wave * 64 + lane;
            gload16(xbc + (tbase + (s >> 2)) * CONVD + h * HD + (s & 3) * 8, XKP + wave * 512);
        }
        if (tid < 64) dtS[tid] = dts[(tbase + tid) * NH + h];
        __syncthreads();
        for (int i = tid; i < 2048; i += 256) {
            int p = i & 31, k = i >> 5;
            XdS[p * 72 + k] = (short)f2bf(bf2f(XKP[k * 32 + p]) * dtS[k] * dkS[hh][k]);
        }
        __syncthreads();
        {
            int ptile = wave & 1;
            bf16x8 a0 = *(const bf16x8*)&XdS[(ptile * 16 + lr) * 72 + lg * 8];
            bf16x8 a1 = *(const bf16x8*)&XdS[(ptile * 16 + lr) * 72 + 32 + lg * 8];
            size_t base = ((size_t)bc * NH + h) * 2048;
            #pragma unroll
            for (int j = 0; j < 2; j++) {
                int nt = (wave >> 1) * 2 + j;
                bf16x8 b0 = *(const bf16x8*)&BT[(nt * 16 + lr) * 72 + lg * 8];
                bf16x8 b1 = *(const bf16x8*)&BT[(nt * 16 + lr) * 72 + 32 + lg * 8];
                f32x4 z = {0.f, 0.f, 0.f, 0.f};
                z = __builtin_amdgcn_mfma_f32_16x16x32_bf16(a0, b0, z, 0, 0, 0);
                z = __builtin_amdgcn_mfma_f32_16x16x32_bf16(a1, b1, z, 0, 0, 0);
                #pragma unroll
                for (int r = 0; r < 4; r++) {
                    int p = ptile * 16 + lg * 4 + r;
                    float v = z[r];
                    float vo = __shfl_xor(v, 1);
                    if (!(lr & 1)) {
                        int chunk = (nt << 1) | (lr >> 3);
                        *(unsigned*)&st16[base + p * 64 + ((chunk ^ (p & 7)) << 3) + (lr & 7)] = cvtpk(v, vo);
                    }
                }
            }
        }
        __syncthreads();
    }
}

// ---------------- k_scan: sequential inter-chunk scan on bf16 states (fp32 accum) ----------------
__global__ __launch_bounds__(256) void k_scan(unsigned* __restrict__ st32, const float* __restrict__ cdec) {
    int bid = blockIdx.x;           // BATCH*NH*4
    int bh = bid >> 2, seg = bid & 3;
    int b = bh >> 4, h = bh & 15;
    int off = seg * 256 + threadIdx.x;   // u32 index within 1024
    float p0 = 0.f, p1 = 0.f;
    for (int c = 0; c < 64; c++) {
        float dec = cdec[bh * 64 + c];
        size_t idx = ((((size_t)b * 64 + c) * NH) + h) * 1024 + off;
        unsigned v = st32[idx];
        float s0 = bf2f((short)(v & 0xffffu));
        float s1 = bf2f((short)(v >> 16));
        st32[idx] = cvtpk(p0, p1);
        p0 = fmaf(dec, p0, s0);
        p1 = fmaf(dec, p1, s1);
    }
}

// ---------------- k_y: Y16 = Y_diag + exp(acs)*(C . prev^T) + D*x ----------------
__global__ __launch_bounds__(256) void k_y(const short* __restrict__ xbc, const float* __restrict__ dts,
                                           const short* __restrict__ st16, const float* __restrict__ acs_g,
                                           const float* __restrict__ D_skip, short* __restrict__ Y16) {
    __shared__ short CsB[64 * 72];   // C[q][n], live throughout
    __shared__ short Wsh[64 * 72];   // B at load; W per head after M
    __shared__ short XtS[32 * 72];   // Xt[p][k] per head (padded, MFMA operand)
    __shared__ __align__(16) short PtL[32 * 64];  // prev tile, linear copy of (swizzled) st16
    __shared__ __align__(16) short XKP[64 * 32];  // raw x tile [k][p]
    __shared__ float acsH[64];
    __shared__ float dtS[64];
    int tid = threadIdx.x;
    int bid = blockIdx.x;
    int hg = bid & 3;
    int bc = bid >> 2;
    int b = bc >> 6, c = bc & 63;
    int h0 = hg * HGRP;
    size_t tbase = (size_t)b * SEQ + (size_t)c * 64;
    int wave = tid >> 6, lane = tid & 63;
    int lr = lane & 15, lg = lane >> 4;

    for (int i = tid; i < 64 * 64; i += 256) {
        int q = i >> 6, n = i & 63;
        const short* rowp = xbc + (tbase + q) * CONVD + DINNER;
        Wsh[q * 72 + n] = rowp[n];            // B (consumed by M, then reused as W)
        CsB[q * 72 + n] = rowp[DSTATE + n];   // C
    }
    __syncthreads();

    // M = C . B^T : wave owns q-strip of 16 rows, kept in regs
    f32x4 macc[4];
    bf16x8 ca0 = *(const bf16x8*)&CsB[(wave * 16 + lr) * 72 + lg * 8];
    bf16x8 ca1 = *(const bf16x8*)&CsB[(wave * 16 + lr) * 72 + 32 + lg * 8];
    {
        #pragma unroll
        for (int ct = 0; ct < 4; ct++) {
            bf16x8 b0 = *(const bf16x8*)&Wsh[(ct * 16 + lr) * 72 + lg * 8];
            bf16x8 b1 = *(const bf16x8*)&Wsh[(ct * 16 + lr) * 72 + 32 + lg * 8];
            f32x4 z = {0.f, 0.f, 0.f, 0.f};
            z = __builtin_amdgcn_mfma_f32_16x16x32_bf16(ca0, b0, z, 0, 0, 0);
            z = __builtin_amdgcn_mfma_f32_16x16x32_bf16(ca1, b1, z, 0, 0, 0);
            macc[ct] = z;
        }
    }
    __syncthreads();   // all waves done reading B before Wsh is overwritten

    for (int hh = 0; hh < HGRP; hh++) {
        int h = h0 + hh;
        // phase 1: issue bulk loads + stage per-head scalars
        {
            int s = wave * 64 + lane;
            gload16(xbc + (tbase + (s >> 2)) * CONVD + h * HD + (s & 3) * 8, XKP + wave * 512);
            gload16(st16 + ((size_t)bc * NH + h) * 2048 + s * 8, PtL + wave * 512);
        }
        if (tid < 64) {
            acsH[tid] = acs_g[(((size_t)(b * NH + h)) * 64 + c) * 64 + tid];
            dtS[tid] = dts[(tbase + tid) * NH + h];
        }
        __syncthreads();
        // phase 2: W build (wave-local rows) + Xt transpose
        #pragma unroll
        for (int ct = 0; ct < 4; ct++) {
            int k = ct * 16 + lr;
            #pragma unroll
            for (int r = 0; r < 4; r++) {
                int q = wave * 16 + lg * 4 + r;
                float wv = 0.f;
                if (k <= q) wv = macc[ct][r] * __expf(acsH[q] - acsH[k]);
                float wo = __shfl_xor(wv, 1);
                if (!(lr & 1))
                    *(unsigned*)&Wsh[q * 72 + k] = cvtpk(wv, wo);
            }
        }
        for (int i = tid; i < 2048; i += 256) {
            int p = i & 31, k = i >> 5;
            XtS[p * 72 + k] = (short)f2bf(bf2f(XKP[k * 32 + p]) * dtS[k]);
        }
        __syncthreads();
        // phase 3: MFMAs + Y write
        float eq[4];
        #pragma unroll
        for (int r = 0; r < 4; r++) eq[r] = __expf(acsH[wave * 16 + lg * 4 + r]);
        float dsk = D_skip[h];
        bf16x8 wa0 = *(const bf16x8*)&Wsh[(wave * 16 + lr) * 72 + lg * 8];
        bf16x8 wa1 = *(const bf16x8*)&Wsh[(wave * 16 + lr) * 72 + 32 + lg * 8];
        #pragma unroll
        for (int pt = 0; pt < 2; pt++) {
            int p = pt * 16 + lr;
            bf16x8 xb0 = *(const bf16x8*)&XtS[p * 72 + lg * 8];
            bf16x8 xb1 = *(const bf16x8*)&XtS[p * 72 + 32 + lg * 8];
            f32x4 zd = {0.f, 0.f, 0.f, 0.f};
            zd = __builtin_amdgcn_mfma_f32_16x16x32_bf16(wa0, xb0, zd, 0, 0, 0);
            zd = __builtin_amdgcn_mfma_f32_16x16x32_bf16(wa1, xb1, zd, 0, 0, 0);
            bf16x8 pb0 = *(const bf16x8*)&PtL[p * 64 + ((lg ^ (p & 7)) << 3)];
            bf16x8 pb1 = *(const bf16x8*)&PtL[p * 64 + (((lg + 4) ^ (p & 7)) << 3)];
            f32x4 zo = {0.f, 0.f, 0.f, 0.f};
            zo = __builtin_amdgcn_mfma_f32_16x16x32_bf16(ca0, pb0, zo, 0, 0, 0);
            zo = __builtin_amdgcn_mfma_f32_16x16x32_bf16(ca1, pb1, zo, 0, 0, 0);
            #pragma unroll
            for (int r = 0; r < 4; r++) {
                int q = wave * 16 + lg * 4 + r;
                float xv = bf2f(XKP[q * 32 + p]);
                float v = zd[r] + eq[r] * zo[r] + dsk * xv;
                float vo = __shfl_xor(v, 1);
                if (!(lr & 1))
                    *(unsigned*)&Y16[((tbase + q) * NH + h) * HD + p] = cvtpk(v, vo);
            }
        }
        __syncthreads();   // protect buffers before next head overwrite
    }
}

extern "C" void kernel_launch(void* const* d_in, const int* in_sizes, int n_in,
                              void* d_out, int out_size, void* d_ws, size_t ws_size,
                              hipStream_t stream) {
    const int*   ids        = (const int*)d_in[0];
    const float* embed_w    = (const float*)d_in[1];
    const float* in_proj_w  = (const float*)d_in[2];
    const float* conv_w     = (const float*)d_in[3];
    const float* conv_b     = (const float*)d_in[4];
    const float* A_log      = (const float*)d_in[5];
    const float* D_skip     = (const float*)d_in[6];
    const float* dt_bias    = (const float*)d_in[7];
    const float* gate_w     = (const float*)d_in[8];
    const float* out_proj_w = (const float*)d_in[9];
    const float* norm_w     = (const float*)d_in[10];
    float* out = (float*)d_out;

    if (ws_size < WS_FLOATS * sizeof(float)) {
        k_diag<<<1, 64, 0, stream>>>(out, (float)(ws_size >> 20));
        return;
    }

    float* ws   = (float*)d_ws;
    short* u16  = (short*)(ws + U16_OFF);
    short* z16  = (short*)(ws + Z16_OFF);
    short* xbc  = (short*)(ws + XBC_OFF);
    float* dts  = ws + DTS_OFF;
    float* acs  = ws + ACS_OFF;
    float* cdec = ws + CDEC_OFF;
    short* Wp   = (short*)(ws + WP_OFF);
    short* Wo   = (short*)(ws + WO_OFF);
    short* We   = (short*)(ws + WE_OFF);
    short* st16 = (short*)(ws + UNION_OFF);                 // bf16 states (swizzled)
    short* Y16  = (short*)(ws + UNION_OFF + Y16_SUB);       // bf16 Y (live through k_outproj)
    short* xf16 = (short*)(ws + UNION_OFF);                 // aliases dead st16

    k_cvt<<<(NPAD * DMODEL + 255) / 256, 256, 0, stream>>>(in_proj_w, Wp, DPROJ * DMODEL, NPAD * DMODEL);
    k_cvt_gate<<<(DMODEL * DINNER + 255) / 256, 256, 0, stream>>>(out_proj_w, gate_w, Wo, DMODEL * DINNER);
    k_cvt<<<(VOCAB * DMODEL + 255) / 256, 256, 0, stream>>>(embed_w, We, VOCAB * DMODEL, VOCAB * DMODEL);
    k_embed<<<TOK, 64, 0, stream>>>(ids, embed_w, norm_w, u16);
    k_gemm_mfma<0><<<(NPAD / 128) * 256, 512, 0, stream>>>(
        u16, Wp, DMODEL, nullptr, z16, xbc, dts, dt_bias, conv_w, conv_b);
    k_states<<<BATCH * 64 * 4, 256, 0, stream>>>(xbc, dts, A_log, st16, acs, cdec);
    k_scan<<<BATCH * NH * 4, 256, 0, stream>>>((unsigned*)st16, cdec);
    k_y<<<BATCH * 64 * 4, 256, 0, stream>>>(xbc, dts, st16, acs, D_skip, Y16);
    k_outproj<<<(DMODEL / 128) * 256, 512, 0, stream>>>(Y16, z16, Wo, ids, embed_w, xf16);
    k_gemm_mfma<2><<<(VOCAB / 128) * 256, 512, 0, stream>>>(
        xf16, We, DMODEL, out, nullptr, nullptr, nullptr, nullptr, nullptr, nullptr);
}

// Round 22
// 210.850 us; speedup vs baseline: 1.2510x; 1.0225x over previous
//
#include <hip/hip_runtime.h>
#include <cstdint>
#include <cstddef>

#define TOK    32768   // B*L
#define BATCH  8
#define SEQ    4096
#define DMODEL 256
#define DINNER 512
#define DSTATE 64
#define NH     16
#define HD     32
#define DPROJ  1168
#define NPAD   1280    // in_proj N padded to 10*128
#define CONVD  640
#define VOCAB  512
#define HGRP   4       // heads per states/y block
#define TS     132     // conv tile LDS stride (shorts)

typedef __attribute__((ext_vector_type(8))) short bf16x8;
typedef __attribute__((ext_vector_type(4))) float f32x4;

__device__ __forceinline__ unsigned short f2bf(float f) {
    unsigned u = __float_as_uint(f);
    u += 0x7fffu + ((u >> 16) & 1u);       // RNE
    return (unsigned short)(u >> 16);
}
__device__ __forceinline__ float bf2f(short s) {
    return __uint_as_float(((unsigned)(unsigned short)s) << 16);
}
// pack two f32 -> two bf16 (RNE) in one instruction
__device__ __forceinline__ unsigned cvtpk(float lo, float hi) {
    unsigned r;
    asm("v_cvt_pk_bf16_f32 %0, %1, %2" : "=v"(r) : "v"(lo), "v"(hi));
    return r;
}
__device__ __forceinline__ float fsilu(float s) {
    return s * __builtin_amdgcn_rcpf(1.f + __expf(-s));
}
__device__ __forceinline__ float sp(float v) {
    return v > 20.f ? v : __logf(1.f + __expf(v));
}

// async global->LDS, 16B per lane; dst wave-uniform base, lane fills dst+lane*16B
__device__ __forceinline__ void gload16(const short* src, short* dst) {
    __builtin_amdgcn_global_load_lds((const __attribute__((address_space(1))) void*)src,
                                     (__attribute__((address_space(3))) void*)dst, 16, 0, 0);
}

// ---------------- ws layout (floats, all 16B aligned) ----------------
#define U16_OFF   0                                    // TOK*256 bf16
#define Z16_OFF   (U16_OFF  + (size_t)TOK*128)         // TOK*512 bf16
#define XBC_OFF   (Z16_OFF  + (size_t)TOK*256)         // TOK*640 bf16
#define DTS_OFF   (XBC_OFF  + (size_t)TOK*320)         // TOK*16 fp32
#define ACS_OFF   (DTS_OFF  + (size_t)TOK*16)
#define CDEC_OFF  (ACS_OFF  + (size_t)BATCH*NH*64*64)
#define WP_OFF    (CDEC_OFF + (size_t)BATCH*NH*64)
#define WO_OFF    (WP_OFF   + 163840)
#define WE_OFF    (WO_OFF   + 65536)
#define UNION_OFF (WE_OFF   + 65536)
// union: [0,TOK*256): st16 bf16 (dead after k_y) -> xf16 bf16
//        [TOK*256,TOK*512): Y16 bf16 (read by k_outproj)
#define UNION_FL  ((size_t)BATCH*64*NH*2048)
#define Y16_SUB   ((size_t)TOK*256)
#define WS_FLOATS (UNION_OFF + UNION_FL)

__global__ void k_diag(float* out, float wsmb) {
    if (blockIdx.x == 0 && threadIdx.x == 0) out[0] = wsmb;
}

// ---------------- weight fp32 -> bf16 (+ zero pad) ----------------
__global__ void k_cvt(const float* __restrict__ s, short* __restrict__ d, int nsrc, int ntot) {
    int i = blockIdx.x * 256 + threadIdx.x;
    if (i < ntot) d[i] = (i < nsrc) ? (short)f2bf(s[i]) : (short)0;
}
// Wo' = Wo * gate_norm_w (folded gate weight; K = DINNER, power of 2)
__global__ void k_cvt_gate(const float* __restrict__ s, const float* __restrict__ gw,
                           short* __restrict__ d, int ntot) {
    int i = blockIdx.x * 256 + threadIdx.x;
    if (i < ntot) d[i] = (short)f2bf(s[i] * gw[i & (DINNER - 1)]);
}

// ---------------- embed gather + rmsnorm -> u16 (bf16) ----------------
__global__ void k_embed(const int* __restrict__ ids, const float* __restrict__ embed,
                        const float* __restrict__ norm_w, short* __restrict__ u16) {
    int t = blockIdx.x;
    int lane = threadIdx.x;   // 64
    int id = ids[t];
    float4 v = ((const float4*)(embed + (size_t)id * DMODEL))[lane];
    float ss = v.x*v.x + v.y*v.y + v.z*v.z + v.w*v.w;
    #pragma unroll
    for (int o = 32; o > 0; o >>= 1) ss += __shfl_down(ss, o);
    ss = __shfl(ss, 0);
    float r = rsqrtf(ss * (1.0f / DMODEL) + 1e-6f);
    float4 w = ((const float4*)norm_w)[lane];
    unsigned p0 = cvtpk(v.x * r * w.x, v.y * r * w.y);
    unsigned p1 = cvtpk(v.z * r * w.z, v.w * r * w.w);
    ((uint2*)(u16 + (size_t)t * DMODEL))[lane] = make_uint2(p0, p1);
}

// ---------------- bf16 MFMA GEMM: 512 threads (8 waves), 128x128 tile, BK=64 ----------------
// T4 counted-vmcnt double-buffer: raw s_barrier + literal vmcnt(N); loads for tile kt+1/kt+2
// stay in flight across the compute of tile kt (never drain to 0 in the main loop).
// Per wave 4 gloads/tile (halo waves +2 VGPR loads -> vmcnt(6) branch, wave-uniform).
// nK = K/64 = 4 for both modes (even -> parity-unrolled halo regs, no rotation copies).
// Rule-#21 swizzle; XCD-aware tile map (T1).
// MODE 0: in_proj (z16 / conv+silu->xbc / dt).  MODE 2: logits fp32.
template<int MODE>
__global__ __launch_bounds__(512) void k_gemm_mfma(
    const short* __restrict__ A, const short* __restrict__ B, int K,
    float* __restrict__ outF, short* __restrict__ z16, short* __restrict__ xbc,
    float* __restrict__ dts, const float* __restrict__ dt_bias,
    const float* __restrict__ cw, const float* __restrict__ cb) {
    // A buf0 | A buf1 | B buf0 | B buf1, each 8192 shorts; conv Tile aliases front 17292
    __shared__ __align__(16) short SM[32768];
    constexpr int NX = (MODE == 0) ? (NPAD / 128) : (VOCAB / 128);
    int tid = threadIdx.x;
    int bid = blockIdx.x;
    int slot = bid >> 3;
    int m0 = (((bid & 7) * 32) + slot / NX) << 7;
    int n0 = (slot % NX) << 7;
    int wave = tid >> 6, lane = tid & 63;
    int wm = wave >> 1, wn = wave & 1;
    int lr = lane & 15, lg = lane >> 4;
    const f32x4 zer = {0.f, 0.f, 0.f, 0.f};
    f32x4 acc[2][4];
    #pragma unroll
    for (int i = 0; i < 2; i++)
        #pragma unroll
        for (int j = 0; j < 4; j++) acc[i][j] = zer;

    const bool isXBC = (MODE == 0) && (n0 >= 512) && (n0 < 1152);
    const bool atStart = (m0 & (SEQ - 1)) == 0;
    const bool haloLane = isXBC && (wm == 0) && !atStart && (lr < 3);
    const bool haloWave = isXBC && (wm == 0) && !atStart;   // wave-uniform
    f32x4 hacc[4];
    #pragma unroll
    for (int j = 0; j < 4; j++) hacc[j] = zer;
    const bf16x8 hz = {0, 0, 0, 0, 0, 0, 0, 0};
    bf16x8 hA0 = hz, hA1 = hz;   // halo regs for even kt
    bf16x8 hB0 = hz, hB1 = hz;   // halo regs for odd kt

    const int nK = K >> 6;       // 4 for both modes
    const int slo = lane >> 3;
    const int skb = ((lane & 7) ^ slo) << 3;

    auto stage = [&](int kt2) {
        int k0 = kt2 << 6;
        int bsel = (kt2 & 1) * 8192;
        #pragma unroll
        for (int j = 0; j < 2; j++) {
            int row = wave * 16 + j * 8 + slo;
            gload16(A + (size_t)(m0 + row) * K + k0 + skb, SM + bsel + (wave * 2 + j) * 512);
            gload16(B + (size_t)(n0 + row) * K + k0 + skb, SM + 16384 + bsel + (wave * 2 + j) * 512);
        }
    };

    // prologue: stage tiles 0 and 1 (+ halo regs)
    stage(0);
    if (haloLane) {
        hA0 = *(const bf16x8*)(A + (size_t)(m0 - 3 + lr) * K + lg * 8);
        hA1 = *(const bf16x8*)(A + (size_t)(m0 - 3 + lr) * K + 32 + lg * 8);
    }
    stage(1);
    if (haloLane) {
        hB0 = *(const bf16x8*)(A + (size_t)(m0 - 3 + lr) * K + 64 + lg * 8);
        hB1 = *(const bf16x8*)(A + (size_t)(m0 - 3 + lr) * K + 96 + lg * 8);
    }

    auto body = [&](int kt, bf16x8& h0, bf16x8& h1) {
        // phase gate: wait own tile-kt loads (tile kt+1/kt+2 stay in flight), publish
        if (kt + 1 < nK) {
            if (haloWave) asm volatile("s_waitcnt vmcnt(6)" ::: "memory");
            else          asm volatile("s_waitcnt vmcnt(4)" ::: "memory");
        } else {
            asm volatile("s_waitcnt vmcnt(0)" ::: "memory");
        }
        __builtin_amdgcn_s_barrier();
        __builtin_amdgcn_sched_barrier(0);
        const short* CA = SM + (kt & 1) * 8192;
        const short* CB = SM + 16384 + (kt & 1) * 8192;
        #pragma unroll
        for (int kk = 0; kk < 2; kk++) {
            int sw = (((kk << 2) + lg) ^ (lr & 7)) << 3;
            bf16x8 af[2], bfr[4];
            #pragma unroll
            for (int mi = 0; mi < 2; mi++)
                af[mi] = *(const bf16x8*)&CA[(wm * 32 + mi * 16 + lr) * 64 + sw];
            #pragma unroll
            for (int ni = 0; ni < 4; ni++)
                bfr[ni] = *(const bf16x8*)&CB[(wn * 64 + ni * 16 + lr) * 64 + sw];
            #pragma unroll
            for (int mi = 0; mi < 2; mi++)
                #pragma unroll
                for (int ni = 0; ni < 4; ni++)
                    acc[mi][ni] = __builtin_amdgcn_mfma_f32_16x16x32_bf16(af[mi], bfr[ni], acc[mi][ni], 0, 0, 0);
            if (isXBC && wm == 0) {
                bf16x8 h = (kk == 0) ? h0 : h1;
                #pragma unroll
                for (int ni = 0; ni < 4; ni++)
                    hacc[ni] = __builtin_amdgcn_mfma_f32_16x16x32_bf16(h, bfr[ni], hacc[ni], 0, 0, 0);
            }
        }
        __builtin_amdgcn_sched_barrier(0);
        __builtin_amdgcn_s_barrier();       // all reads of buf(kt&1) retired
        __builtin_amdgcn_sched_barrier(0);
        if (kt + 2 < nK) {
            stage(kt + 2);                  // into buf(kt&1), just freed
            if (haloLane) {
                int k0 = (kt + 2) << 6;
                h0 = *(const bf16x8*)(A + (size_t)(m0 - 3 + lr) * K + k0 + lg * 8);
                h1 = *(const bf16x8*)(A + (size_t)(m0 - 3 + lr) * K + k0 + 32 + lg * 8);
            }
        }
    };

    for (int kt = 0; kt < nK; kt += 2) {
        body(kt, hA0, hA1);
        body(kt + 1, hB0, hB1);
    }

    if (isXBC) {
        // ---- fused causal conv(k=4) + SiLU, sliding-window epilogue ----
        short* Tile = SM;   // [131][TS]: rows 0-2 = halo, 3+row = token m0+row
        __syncthreads();    // last tile's ds_reads done before aliasing
        #pragma unroll
        for (int mi = 0; mi < 2; mi++)
            #pragma unroll
            for (int ni = 0; ni < 4; ni++)
                #pragma unroll
                for (int r = 0; r < 4; r++) {
                    int row = wm * 32 + mi * 16 + lg * 4 + r;
                    int col = wn * 64 + ni * 16 + lr;
                    float v = acc[mi][ni][r];
                    float vo = __shfl_xor(v, 1);
                    if (!(lr & 1))
                        *(unsigned*)&Tile[(3 + row) * TS + col] = cvtpk(v, vo);
                }
        if (wm == 0 && lg == 0) {
            #pragma unroll
            for (int ni = 0; ni < 4; ni++)
                #pragma unroll
                for (int r = 0; r < 3; r++)
                    Tile[r * TS + wn * 64 + ni * 16 + lr] = (short)f2bf(hacc[ni][r]);
        }
        __syncthreads();
        int cp = tid & 63, rg = tid >> 6;   // 64 col-pairs x 8 row groups of 16
        int colb = cp * 2;
        int ch = (n0 - 512) + colb;
        float c0w0 = cw[ch * 4], c0w1 = cw[ch * 4 + 1], c0w2 = cw[ch * 4 + 2], c0w3 = cw[ch * 4 + 3];
        float c1w0 = cw[ch * 4 + 4], c1w1 = cw[ch * 4 + 5], c1w2 = cw[ch * 4 + 6], c1w3 = cw[ch * 4 + 7];
        float b0v = cb[ch], b1v = cb[ch + 1];
        int rbase = rg * 16;
        unsigned w0 = *(const unsigned*)&Tile[(rbase + 0) * TS + colb];
        unsigned w1 = *(const unsigned*)&Tile[(rbase + 1) * TS + colb];
        unsigned w2 = *(const unsigned*)&Tile[(rbase + 2) * TS + colb];
        for (int i = 0; i < 16; i++) {
            unsigned w3 = *(const unsigned*)&Tile[(rbase + i + 3) * TS + colb];
            float s0 = b0v, s1 = b1v;
            s0 = fmaf(bf2f((short)(w0 & 0xffffu)), c0w0, s0); s1 = fmaf(bf2f((short)(w0 >> 16)), c1w0, s1);
            s0 = fmaf(bf2f((short)(w1 & 0xffffu)), c0w1, s0); s1 = fmaf(bf2f((short)(w1 >> 16)), c1w1, s1);
            s0 = fmaf(bf2f((short)(w2 & 0xffffu)), c0w2, s0); s1 = fmaf(bf2f((short)(w2 >> 16)), c1w2, s1);
            s0 = fmaf(bf2f((short)(w3 & 0xffffu)), c0w3, s0); s1 = fmaf(bf2f((short)(w3 >> 16)), c1w3, s1);
            s0 = fsilu(s0);
            s1 = fsilu(s1);
            *(unsigned*)&xbc[(size_t)(m0 + rbase + i) * CONVD + ch] = cvtpk(s0, s1);
            w0 = w1; w1 = w2; w2 = w3;
        }
        return;
    }

    #pragma unroll
    for (int mi = 0; mi < 2; mi++) {
        #pragma unroll
        for (int r = 0; r < 4; r++) {
            int row = m0 + wm * 32 + mi * 16 + lg * 4 + r;
            #pragma unroll
            for (int ni = 0; ni < 4; ni++) {
                int col = n0 + wn * 64 + ni * 16 + lr;
                float v = acc[mi][ni][r];
                if (MODE == 0) {
                    if (n0 < 512) {
                        float vo = __shfl_xor(v, 1);
                        if (!(lr & 1))
                            *(unsigned*)&z16[(size_t)row * DINNER + col] = cvtpk(v, vo);
                    } else if (wn == 0 && ni == 0) {
                        dts[(size_t)row * NH + lr] = sp(v + dt_bias[lr]);
                    }
                } else {
                    outF[(size_t)row * VOCAB + col] = v;
                }
            }
        }
    }
}

// ---------------- k_outproj: xf16 = bf16( rms(g)[m] * (g @ Wo'^T) + embed[ids] ) ----------------
__global__ __launch_bounds__(512) void k_outproj(
    const short* __restrict__ Y16, const short* __restrict__ z16,
    const short* __restrict__ Wo, const int* __restrict__ ids,
    const float* __restrict__ embed, short* __restrict__ xf16) {
    __shared__ __align__(16) short As[8192];
    __shared__ __align__(16) short Bs[8192];
    __shared__ float rmsS[128];
    int tid = threadIdx.x;
    int bid = blockIdx.x;                 // 512 blocks: 8 xcd x 32 m x 2 n
    int slot = bid >> 3;
    int m0 = (((bid & 7) * 32) + (slot >> 1)) << 7;
    int n0 = (slot & 1) << 7;
    int wave = tid >> 6, lane = tid & 63;
    int wm = wave >> 1, wn = wave & 1;
    int lr = lane & 15, lg = lane >> 4;
    const f32x4 zer = {0.f, 0.f, 0.f, 0.f};
    f32x4 acc[2][4];
    #pragma unroll
    for (int i = 0; i < 2; i++)
        #pragma unroll
        for (int j = 0; j < 4; j++) acc[i][j] = zer;

    const int arow = tid >> 2;            // A staging: row 0..127
    const int ac0 = (tid & 3) * 2;        // two 8-short chunks per thread
    const int slo = lane >> 3;
    const int skb = ((lane & 7) ^ slo) << 3;
    float ssq = 0.f;

    for (int kt = 0; kt < 8; ++kt) {
        int k0 = kt << 6;
        #pragma unroll
        for (int j = 0; j < 2; j++) {
            int row = wave * 16 + j * 8 + slo;
            gload16(Wo + (size_t)(n0 + row) * DINNER + k0 + skb, Bs + (wave * 2 + j) * 512);
        }
        union { int4 v; short s[8]; } y0u, y1u, z0u, z1u;
        const size_t rbase = (size_t)(m0 + arow) * DINNER + k0 + ac0 * 8;
        y0u.v = *(const int4*)(Y16 + rbase);
        y1u.v = *(const int4*)(Y16 + rbase + 8);
        z0u.v = *(const int4*)(z16 + rbase);
        z1u.v = *(const int4*)(z16 + rbase + 8);
        unsigned pk[8];
        #pragma unroll
        for (int e = 0; e < 4; e++) {
            float g0 = bf2f(y0u.s[2*e])     * fsilu(bf2f(z0u.s[2*e]));
            float g1 = bf2f(y0u.s[2*e + 1]) * fsilu(bf2f(z0u.s[2*e + 1]));
            ssq += g0 * g0 + g1 * g1;
            pk[e] = cvtpk(g0, g1);
        }
        #pragma unroll
        for (int e = 0; e < 4; e++) {
            float g0 = bf2f(y1u.s[2*e])     * fsilu(bf2f(z1u.s[2*e]));
            float g1 = bf2f(y1u.s[2*e + 1]) * fsilu(bf2f(z1u.s[2*e + 1]));
            ssq += g0 * g0 + g1 * g1;
            pk[4 + e] = cvtpk(g0, g1);
        }
        *(int4*)&As[arow * 64 + ((ac0 ^ (arow & 7)) << 3)] = *(int4*)&pk[0];
        *(int4*)&As[arow * 64 + (((ac0 + 1) ^ (arow & 7)) << 3)] = *(int4*)&pk[4];
        __syncthreads();   // drains gload vmcnt + ds_writes: tile kt ready
        #pragma unroll
        for (int kk = 0; kk < 2; kk++) {
            int sw = (((kk << 2) + lg) ^ (lr & 7)) << 3;
            bf16x8 af[2], bfr[4];
            #pragma unroll
            for (int mi = 0; mi < 2; mi++)
                af[mi] = *(const bf16x8*)&As[(wm * 32 + mi * 16 + lr) * 64 + sw];
            #pragma unroll
            for (int ni = 0; ni < 4; ni++)
                bfr[ni] = *(const bf16x8*)&Bs[(wn * 64 + ni * 16 + lr) * 64 + sw];
            #pragma unroll
            for (int mi = 0; mi < 2; mi++)
                #pragma unroll
                for (int ni = 0; ni < 4; ni++)
                    acc[mi][ni] = __builtin_amdgcn_mfma_f32_16x16x32_bf16(af[mi], bfr[ni], acc[mi][ni], 0, 0, 0);
        }
        __syncthreads();   // all reads done before next overwrite
    }
    // per-row rms: reduce sumsq across the 4 staging threads of each row
    ssq += __shfl_xor(ssq, 1);
    ssq += __shfl_xor(ssq, 2);
    if ((tid & 3) == 0) rmsS[arow] = rsqrtf(ssq * (1.0f / DINNER) + 1e-5f);
    __syncthreads();

    #pragma unroll
    for (int mi = 0; mi < 2; mi++) {
        #pragma unroll
        for (int r = 0; r < 4; r++) {
            int rl = wm * 32 + mi * 16 + lg * 4 + r;
            int row = m0 + rl;
            int id = ids[row];
            float rm = rmsS[rl];
            #pragma unroll
            for (int ni = 0; ni < 4; ni++) {
                int col = n0 + wn * 64 + ni * 16 + lr;
                float v = acc[mi][ni][r] * rm;
                float vo = __shfl_xor(v, 1);
                if (!(lr & 1)) {
                    float2 res = *(const float2*)&embed[(size_t)id * DMODEL + col];
                    *(unsigned*)&xf16[(size_t)row * DMODEL + col] = cvtpk(v + res.x, vo + res.y);
                }
            }
        }
    }
}

// ---------------- k_states: per (b,c,hg): chunk states, bulk-staged x, swizzled st16 write ----------------
__global__ __launch_bounds__(256) void k_states(const short* __restrict__ xbc, const float* __restrict__ dts,
                                                const float* __restrict__ A_log,
                                                short* __restrict__ st16,
                                                float* __restrict__ acs_g, float* __restrict__ cdec) {
    __shared__ short BsB[64 * 72];   // B[k][n]
    __shared__ short BT[64 * 72];    // B^T[n][k], built once
    __shared__ short XdS[32 * 72];   // Xd[p][k] per head (padded, MFMA operand)
    __shared__ __align__(16) short XKP[64 * 32];  // raw x tile [k][p], gload16 target
    __shared__ float dkS[HGRP][64];
    __shared__ float dtS[64];
    int tid = threadIdx.x;
    int bid = blockIdx.x;
    int hg = bid & 3;
    int bc = bid >> 2;
    int b = bc >> 6, c = bc & 63;
    int h0 = hg * HGRP;
    size_t tbase = (size_t)b * SEQ + (size_t)c * 64;
    int wave = tid >> 6, lane = tid & 63;
    int lr = lane & 15, lg = lane >> 4;

    for (int i = tid; i < 64 * 64; i += 256) {
        int q = i >> 6, n = i & 63;
        BsB[q * 72 + n] = xbc[(tbase + q) * CONVD + DINNER + n];
    }
    {
        int h = h0 + wave;
        float Ah = -__expf(A_log[h]);
        float v = dts[(tbase + lane) * NH + h] * Ah;
        #pragma unroll
        for (int off = 1; off < 64; off <<= 1) {
            float o = __shfl_up(v, off);
            if (lane >= off) v += o;
        }
        acs_g[(((size_t)(b * NH + h)) * 64 + c) * 64 + lane] = v;
        float alast = __shfl(v, 63);
        dkS[wave][lane] = __expf(alast - v);
        if (lane == 0) cdec[(b * NH + h) * 64 + c] = __expf(alast);
    }
    __syncthreads();
    for (int i = tid; i < 64 * 64; i += 256) {
        int k = i >> 6, n = i & 63;
        BT[n * 72 + k] = BsB[k * 72 + n];
    }

    for (int hh = 0; hh < HGRP; hh++) {
        int h = h0 + hh;
        {
            int s = wave * 64 + lane;
            gload16(xbc + (tbase + (s >> 2)) * CONVD + h * HD + (s & 3) * 8, XKP + wave * 512);
        }
        if (tid < 64) dtS[tid] = dts[(tbase + tid) * NH + h];
        __syncthreads();
        for (int i = tid; i < 2048; i += 256) {
            int p = i & 31, k = i >> 5;
            XdS[p * 72 + k] = (short)f2bf(bf2f(XKP[k * 32 + p]) * dtS[k] * dkS[hh][k]);
        }
        __syncthreads();
        {
            int ptile = wave & 1;
            bf16x8 a0 = *(const bf16x8*)&XdS[(ptile * 16 + lr) * 72 + lg * 8];
            bf16x8 a1 = *(const bf16x8*)&XdS[(ptile * 16 + lr) * 72 + 32 + lg * 8];
            size_t base = ((size_t)bc * NH + h) * 2048;
            #pragma unroll
            for (int j = 0; j < 2; j++) {
                int nt = (wave >> 1) * 2 + j;
                bf16x8 b0 = *(const bf16x8*)&BT[(nt * 16 + lr) * 72 + lg * 8];
                bf16x8 b1 = *(const bf16x8*)&BT[(nt * 16 + lr) * 72 + 32 + lg * 8];
                f32x4 z = {0.f, 0.f, 0.f, 0.f};
                z = __builtin_amdgcn_mfma_f32_16x16x32_bf16(a0, b0, z, 0, 0, 0);
                z = __builtin_amdgcn_mfma_f32_16x16x32_bf16(a1, b1, z, 0, 0, 0);
                #pragma unroll
                for (int r = 0; r < 4; r++) {
                    int p = ptile * 16 + lg * 4 + r;
                    float v = z[r];
                    float vo = __shfl_xor(v, 1);
                    if (!(lr & 1)) {
                        int chunk = (nt << 1) | (lr >> 3);
                        *(unsigned*)&st16[base + p * 64 + ((chunk ^ (p & 7)) << 3) + (lr & 7)] = cvtpk(v, vo);
                    }
                }
            }
        }
        __syncthreads();
    }
}

// ---------------- k_scan: sequential inter-chunk scan on bf16 states (fp32 accum) ----------------
__global__ __launch_bounds__(256) void k_scan(unsigned* __restrict__ st32, const float* __restrict__ cdec) {
    int bid = blockIdx.x;           // BATCH*NH*4
    int bh = bid >> 2, seg = bid & 3;
    int b = bh >> 4, h = bh & 15;
    int off = seg * 256 + threadIdx.x;   // u32 index within 1024
    float p0 = 0.f, p1 = 0.f;
    for (int c = 0; c < 64; c++) {
        float dec = cdec[bh * 64 + c];
        size_t idx = ((((size_t)b * 64 + c) * NH) + h) * 1024 + off;
        unsigned v = st32[idx];
        float s0 = bf2f((short)(v & 0xffffu));
        float s1 = bf2f((short)(v >> 16));
        st32[idx] = cvtpk(p0, p1);
        p0 = fmaf(dec, p0, s0);
        p1 = fmaf(dec, p1, s1);
    }
}

// ---------------- k_y: Y16 = Y_diag + exp(acs)*(C . prev^T) + D*x ----------------
__global__ __launch_bounds__(256) void k_y(const short* __restrict__ xbc, const float* __restrict__ dts,
                                           const short* __restrict__ st16, const float* __restrict__ acs_g,
                                           const float* __restrict__ D_skip, short* __restrict__ Y16) {
    __shared__ short CsB[64 * 72];   // C[q][n], live throughout
    __shared__ short Wsh[64 * 72];   // B at load; W per head after M
    __shared__ short XtS[32 * 72];   // Xt[p][k] per head (padded, MFMA operand)
    __shared__ __align__(16) short PtL[32 * 64];  // prev tile, linear copy of (swizzled) st16
    __shared__ __align__(16) short XKP[64 * 32];  // raw x tile [k][p]
    __shared__ float acsH[64];
    __shared__ float dtS[64];
    int tid = threadIdx.x;
    int bid = blockIdx.x;
    int hg = bid & 3;
    int bc = bid >> 2;
    int b = bc >> 6, c = bc & 63;
    int h0 = hg * HGRP;
    size_t tbase = (size_t)b * SEQ + (size_t)c * 64;
    int wave = tid >> 6, lane = tid & 63;
    int lr = lane & 15, lg = lane >> 4;

    for (int i = tid; i < 64 * 64; i += 256) {
        int q = i >> 6, n = i & 63;
        const short* rowp = xbc + (tbase + q) * CONVD + DINNER;
        Wsh[q * 72 + n] = rowp[n];            // B (consumed by M, then reused as W)
        CsB[q * 72 + n] = rowp[DSTATE + n];   // C
    }
    __syncthreads();

    // M = C . B^T : wave owns q-strip of 16 rows, kept in regs
    f32x4 macc[4];
    bf16x8 ca0 = *(const bf16x8*)&CsB[(wave * 16 + lr) * 72 + lg * 8];
    bf16x8 ca1 = *(const bf16x8*)&CsB[(wave * 16 + lr) * 72 + 32 + lg * 8];
    {
        #pragma unroll
        for (int ct = 0; ct < 4; ct++) {
            bf16x8 b0 = *(const bf16x8*)&Wsh[(ct * 16 + lr) * 72 + lg * 8];
            bf16x8 b1 = *(const bf16x8*)&Wsh[(ct * 16 + lr) * 72 + 32 + lg * 8];
            f32x4 z = {0.f, 0.f, 0.f, 0.f};
            z = __builtin_amdgcn_mfma_f32_16x16x32_bf16(ca0, b0, z, 0, 0, 0);
            z = __builtin_amdgcn_mfma_f32_16x16x32_bf16(ca1, b1, z, 0, 0, 0);
            macc[ct] = z;
        }
    }
    __syncthreads();   // all waves done reading B before Wsh is overwritten

    for (int hh = 0; hh < HGRP; hh++) {
        int h = h0 + hh;
        // phase 1: issue bulk loads + stage per-head scalars
        {
            int s = wave * 64 + lane;
            gload16(xbc + (tbase + (s >> 2)) * CONVD + h * HD + (s & 3) * 8, XKP + wave * 512);
            gload16(st16 + ((size_t)bc * NH + h) * 2048 + s * 8, PtL + wave * 512);
        }
        if (tid < 64) {
            acsH[tid] = acs_g[(((size_t)(b * NH + h)) * 64 + c) * 64 + tid];
            dtS[tid] = dts[(tbase + tid) * NH + h];
        }
        __syncthreads();
        // phase 2: W build (wave-local rows) + Xt transpose
        #pragma unroll
        for (int ct = 0; ct < 4; ct++) {
            int k = ct * 16 + lr;
            #pragma unroll
            for (int r = 0; r < 4; r++) {
                int q = wave * 16 + lg * 4 + r;
                float wv = 0.f;
                if (k <= q) wv = macc[ct][r] * __expf(acsH[q] - acsH[k]);
                float wo = __shfl_xor(wv, 1);
                if (!(lr & 1))
                    *(unsigned*)&Wsh[q * 72 + k] = cvtpk(wv, wo);
            }
        }
        for (int i = tid; i < 2048; i += 256) {
            int p = i & 31, k = i >> 5;
            XtS[p * 72 + k] = (short)f2bf(bf2f(XKP[k * 32 + p]) * dtS[k]);
        }
        __syncthreads();
        // phase 3: MFMAs + Y write
        float eq[4];
        #pragma unroll
        for (int r = 0; r < 4; r++) eq[r] = __expf(acsH[wave * 16 + lg * 4 + r]);
        float dsk = D_skip[h];
        bf16x8 wa0 = *(const bf16x8*)&Wsh[(wave * 16 + lr) * 72 + lg * 8];
        bf16x8 wa1 = *(const bf16x8*)&Wsh[(wave * 16 + lr) * 72 + 32 + lg * 8];
        #pragma unroll
        for (int pt = 0; pt < 2; pt++) {
            int p = pt * 16 + lr;
            bf16x8 xb0 = *(const bf16x8*)&XtS[p * 72 + lg * 8];
            bf16x8 xb1 = *(const bf16x8*)&XtS[p * 72 + 32 + lg * 8];
            f32x4 zd = {0.f, 0.f, 0.f, 0.f};
            zd = __builtin_amdgcn_mfma_f32_16x16x32_bf16(wa0, xb0, zd, 0, 0, 0);
            zd = __builtin_amdgcn_mfma_f32_16x16x32_bf16(wa1, xb1, zd, 0, 0, 0);
            bf16x8 pb0 = *(const bf16x8*)&PtL[p * 64 + ((lg ^ (p & 7)) << 3)];
            bf16x8 pb1 = *(const bf16x8*)&PtL[p * 64 + (((lg + 4) ^ (p & 7)) << 3)];
            f32x4 zo = {0.f, 0.f, 0.f, 0.f};
            zo = __builtin_amdgcn_mfma_f32_16x16x32_bf16(ca0, pb0, zo, 0, 0, 0);
            zo = __builtin_amdgcn_mfma_f32_16x16x32_bf16(ca1, pb1, zo, 0, 0, 0);
            #pragma unroll
            for (int r = 0; r < 4; r++) {
                int q = wave * 16 + lg * 4 + r;
                float xv = bf2f(XKP[q * 32 + p]);
                float v = zd[r] + eq[r] * zo[r] + dsk * xv;
                float vo = __shfl_xor(v, 1);
                if (!(lr & 1))
                    *(unsigned*)&Y16[((tbase + q) * NH + h) * HD + p] = cvtpk(v, vo);
            }
        }
        __syncthreads();   // protect buffers before next head overwrite
    }
}

extern "C" void kernel_launch(void* const* d_in, const int* in_sizes, int n_in,
                              void* d_out, int out_size, void* d_ws, size_t ws_size,
                              hipStream_t stream) {
    const int*   ids        = (const int*)d_in[0];
    const float* embed_w    = (const float*)d_in[1];
    const float* in_proj_w  = (const float*)d_in[2];
    const float* conv_w     = (const float*)d_in[3];
    const float* conv_b     = (const float*)d_in[4];
    const float* A_log      = (const float*)d_in[5];
    const float* D_skip     = (const float*)d_in[6];
    const float* dt_bias    = (const float*)d_in[7];
    const float* gate_w     = (const float*)d_in[8];
    const float* out_proj_w = (const float*)d_in[9];
    const float* norm_w     = (const float*)d_in[10];
    float* out = (float*)d_out;

    if (ws_size < WS_FLOATS * sizeof(float)) {
        k_diag<<<1, 64, 0, stream>>>(out, (float)(ws_size >> 20));
        return;
    }

    float* ws   = (float*)d_ws;
    short* u16  = (short*)(ws + U16_OFF);
    short* z16  = (short*)(ws + Z16_OFF);
    short* xbc  = (short*)(ws + XBC_OFF);
    float* dts  = ws + DTS_OFF;
    float* acs  = ws + ACS_OFF;
    float* cdec = ws + CDEC_OFF;
    short* Wp   = (short*)(ws + WP_OFF);
    short* Wo   = (short*)(ws + WO_OFF);
    short* We   = (short*)(ws + WE_OFF);
    short* st16 = (short*)(ws + UNION_OFF);                 // bf16 states (swizzled)
    short* Y16  = (short*)(ws + UNION_OFF + Y16_SUB);       // bf16 Y (live through k_outproj)
    short* xf16 = (short*)(ws + UNION_OFF);                 // aliases dead st16

    k_cvt<<<(NPAD * DMODEL + 255) / 256, 256, 0, stream>>>(in_proj_w, Wp, DPROJ * DMODEL, NPAD * DMODEL);
    k_cvt_gate<<<(DMODEL * DINNER + 255) / 256, 256, 0, stream>>>(out_proj_w, gate_w, Wo, DMODEL * DINNER);
    k_cvt<<<(VOCAB * DMODEL + 255) / 256, 256, 0, stream>>>(embed_w, We, VOCAB * DMODEL, VOCAB * DMODEL);
    k_embed<<<TOK, 64, 0, stream>>>(ids, embed_w, norm_w, u16);
    k_gemm_mfma<0><<<(NPAD / 128) * 256, 512, 0, stream>>>(
        u16, Wp, DMODEL, nullptr, z16, xbc, dts, dt_bias, conv_w, conv_b);
    k_states<<<BATCH * 64 * 4, 256, 0, stream>>>(xbc, dts, A_log, st16, acs, cdec);
    k_scan<<<BATCH * NH * 4, 256, 0, stream>>>((unsigned*)st16, cdec);
    k_y<<<BATCH * 64 * 4, 256, 0, stream>>>(xbc, dts, st16, acs, D_skip, Y16);
    k_outproj<<<(DMODEL / 128) * 256, 512, 0, stream>>>(Y16, z16, Wo, ids, embed_w, xf16);
    k_gemm_mfma<2><<<(VOCAB / 128) * 256, 512, 0, stream>>>(
        xf16, We, DMODEL, out, nullptr, nullptr, nullptr, nullptr, nullptr, nullptr);
}

// Round 23
// 210.589 us; speedup vs baseline: 1.2525x; 1.0012x over previous
//
#include <hip/hip_runtime.h>
#include <cstdint>
#include <cstddef>

#define TOK    32768   // B*L
#define BATCH  8
#define SEQ    4096
#define DMODEL 256
#define DINNER 512
#define DSTATE 64
#define NH     16
#define HD     32
#define DPROJ  1168
#define NPAD   1280    // in_proj N padded to 10*128
#define CONVD  640
#define VOCAB  512
#define HGRP   4       // heads per states/y block
#define TS     132     // conv tile LDS stride (shorts)

typedef __attribute__((ext_vector_type(8))) short bf16x8;
typedef __attribute__((ext_vector_type(4))) float f32x4;

__device__ __forceinline__ unsigned short f2bf(float f) {
    unsigned u = __float_as_uint(f);
    u += 0x7fffu + ((u >> 16) & 1u);       // RNE
    return (unsigned short)(u >> 16);
}
__device__ __forceinline__ float bf2f(short s) {
    return __uint_as_float(((unsigned)(unsigned short)s) << 16);
}
// pack two f32 -> two bf16 (RNE) in one instruction
__device__ __forceinline__ unsigned cvtpk(float lo, float hi) {
    unsigned r;
    asm("v_cvt_pk_bf16_f32 %0, %1, %2" : "=v"(r) : "v"(lo), "v"(hi));
    return r;
}
__device__ __forceinline__ float fsilu(float s) {
    return s * __builtin_amdgcn_rcpf(1.f + __expf(-s));
}
__device__ __forceinline__ float sp(float v) {
    return v > 20.f ? v : __logf(1.f + __expf(v));
}

// async global->LDS, 16B per lane; dst wave-uniform base, lane fills dst+lane*16B
__device__ __forceinline__ void gload16(const short* src, short* dst) {
    __builtin_amdgcn_global_load_lds((const __attribute__((address_space(1))) void*)src,
                                     (__attribute__((address_space(3))) void*)dst, 16, 0, 0);
}

// ---------------- ws layout (floats, all 16B aligned) ----------------
#define U16_OFF   0                                    // TOK*256 bf16
#define Z16_OFF   (U16_OFF  + (size_t)TOK*128)         // TOK*512 bf16
#define XBC_OFF   (Z16_OFF  + (size_t)TOK*256)         // TOK*640 bf16
#define DTS_OFF   (XBC_OFF  + (size_t)TOK*320)         // TOK*16 fp32
#define ACS_OFF   (DTS_OFF  + (size_t)TOK*16)
#define CDEC_OFF  (ACS_OFF  + (size_t)BATCH*NH*64*64)
#define WP_OFF    (CDEC_OFF + (size_t)BATCH*NH*64)
#define WO_OFF    (WP_OFF   + 163840)
#define WE_OFF    (WO_OFF   + 65536)
#define UNION_OFF (WE_OFF   + 65536)
// union: [0,TOK*256): st16 bf16 (dead after k_y) -> xf16 bf16
//        [TOK*256,TOK*512): Y16 bf16 (read by k_outproj)
#define UNION_FL  ((size_t)BATCH*64*NH*2048)
#define Y16_SUB   ((size_t)TOK*256)
#define WS_FLOATS (UNION_OFF + UNION_FL)

__global__ void k_diag(float* out, float wsmb) {
    if (blockIdx.x == 0 && threadIdx.x == 0) out[0] = wsmb;
}

// ---------------- weight fp32 -> bf16 (+ zero pad) ----------------
__global__ void k_cvt(const float* __restrict__ s, short* __restrict__ d, int nsrc, int ntot) {
    int i = blockIdx.x * 256 + threadIdx.x;
    if (i < ntot) d[i] = (i < nsrc) ? (short)f2bf(s[i]) : (short)0;
}
// Wo' = Wo * gate_norm_w (folded gate weight; K = DINNER, power of 2)
__global__ void k_cvt_gate(const float* __restrict__ s, const float* __restrict__ gw,
                           short* __restrict__ d, int ntot) {
    int i = blockIdx.x * 256 + threadIdx.x;
    if (i < ntot) d[i] = (short)f2bf(s[i] * gw[i & (DINNER - 1)]);
}

// ---------------- embed gather + rmsnorm -> u16 (bf16) ----------------
__global__ void k_embed(const int* __restrict__ ids, const float* __restrict__ embed,
                        const float* __restrict__ norm_w, short* __restrict__ u16) {
    int t = blockIdx.x;
    int lane = threadIdx.x;   // 64
    int id = ids[t];
    float4 v = ((const float4*)(embed + (size_t)id * DMODEL))[lane];
    float ss = v.x*v.x + v.y*v.y + v.z*v.z + v.w*v.w;
    #pragma unroll
    for (int o = 32; o > 0; o >>= 1) ss += __shfl_down(ss, o);
    ss = __shfl(ss, 0);
    float r = rsqrtf(ss * (1.0f / DMODEL) + 1e-6f);
    float4 w = ((const float4*)norm_w)[lane];
    unsigned p0 = cvtpk(v.x * r * w.x, v.y * r * w.y);
    unsigned p1 = cvtpk(v.z * r * w.z, v.w * r * w.w);
    ((uint2*)(u16 + (size_t)t * DMODEL))[lane] = make_uint2(p0, p1);
}

// ---------------- bf16 MFMA GEMM: 512 threads (8 waves), 128x128 tile, BK=64 ----------------
// T4 counted-vmcnt double-buffer (R22 structure, best known).
// MODE 0: in_proj (z16 / conv+silu->xbc / dt).  MODE 2: logits fp32 (packed float2 stores).
template<int MODE>
__global__ __launch_bounds__(512) void k_gemm_mfma(
    const short* __restrict__ A, const short* __restrict__ B, int K,
    float* __restrict__ outF, short* __restrict__ z16, short* __restrict__ xbc,
    float* __restrict__ dts, const float* __restrict__ dt_bias,
    const float* __restrict__ cw, const float* __restrict__ cb) {
    // A buf0 | A buf1 | B buf0 | B buf1, each 8192 shorts; conv Tile aliases front 17292
    __shared__ __align__(16) short SM[32768];
    constexpr int NX = (MODE == 0) ? (NPAD / 128) : (VOCAB / 128);
    int tid = threadIdx.x;
    int bid = blockIdx.x;
    int slot = bid >> 3;
    int m0 = (((bid & 7) * 32) + slot / NX) << 7;
    int n0 = (slot % NX) << 7;
    int wave = tid >> 6, lane = tid & 63;
    int wm = wave >> 1, wn = wave & 1;
    int lr = lane & 15, lg = lane >> 4;
    const f32x4 zer = {0.f, 0.f, 0.f, 0.f};
    f32x4 acc[2][4];
    #pragma unroll
    for (int i = 0; i < 2; i++)
        #pragma unroll
        for (int j = 0; j < 4; j++) acc[i][j] = zer;

    const bool isXBC = (MODE == 0) && (n0 >= 512) && (n0 < 1152);
    const bool atStart = (m0 & (SEQ - 1)) == 0;
    const bool haloLane = isXBC && (wm == 0) && !atStart && (lr < 3);
    const bool haloWave = isXBC && (wm == 0) && !atStart;   // wave-uniform
    f32x4 hacc[4];
    #pragma unroll
    for (int j = 0; j < 4; j++) hacc[j] = zer;
    const bf16x8 hz = {0, 0, 0, 0, 0, 0, 0, 0};
    bf16x8 hA0 = hz, hA1 = hz;   // halo regs for even kt
    bf16x8 hB0 = hz, hB1 = hz;   // halo regs for odd kt

    const int nK = K >> 6;       // 4 for both modes
    const int slo = lane >> 3;
    const int skb = ((lane & 7) ^ slo) << 3;

    auto stage = [&](int kt2) {
        int k0 = kt2 << 6;
        int bsel = (kt2 & 1) * 8192;
        #pragma unroll
        for (int j = 0; j < 2; j++) {
            int row = wave * 16 + j * 8 + slo;
            gload16(A + (size_t)(m0 + row) * K + k0 + skb, SM + bsel + (wave * 2 + j) * 512);
            gload16(B + (size_t)(n0 + row) * K + k0 + skb, SM + 16384 + bsel + (wave * 2 + j) * 512);
        }
    };

    // prologue: stage tiles 0 and 1 (+ halo regs)
    stage(0);
    if (haloLane) {
        hA0 = *(const bf16x8*)(A + (size_t)(m0 - 3 + lr) * K + lg * 8);
        hA1 = *(const bf16x8*)(A + (size_t)(m0 - 3 + lr) * K + 32 + lg * 8);
    }
    stage(1);
    if (haloLane) {
        hB0 = *(const bf16x8*)(A + (size_t)(m0 - 3 + lr) * K + 64 + lg * 8);
        hB1 = *(const bf16x8*)(A + (size_t)(m0 - 3 + lr) * K + 96 + lg * 8);
    }

    auto body = [&](int kt, bf16x8& h0, bf16x8& h1) {
        // phase gate: wait own tile-kt loads (tile kt+1/kt+2 stay in flight), publish
        if (kt + 1 < nK) {
            if (haloWave) asm volatile("s_waitcnt vmcnt(6)" ::: "memory");
            else          asm volatile("s_waitcnt vmcnt(4)" ::: "memory");
        } else {
            asm volatile("s_waitcnt vmcnt(0)" ::: "memory");
        }
        __builtin_amdgcn_s_barrier();
        __builtin_amdgcn_sched_barrier(0);
        const short* CA = SM + (kt & 1) * 8192;
        const short* CB = SM + 16384 + (kt & 1) * 8192;
        #pragma unroll
        for (int kk = 0; kk < 2; kk++) {
            int sw = (((kk << 2) + lg) ^ (lr & 7)) << 3;
            bf16x8 af[2], bfr[4];
            #pragma unroll
            for (int mi = 0; mi < 2; mi++)
                af[mi] = *(const bf16x8*)&CA[(wm * 32 + mi * 16 + lr) * 64 + sw];
            #pragma unroll
            for (int ni = 0; ni < 4; ni++)
                bfr[ni] = *(const bf16x8*)&CB[(wn * 64 + ni * 16 + lr) * 64 + sw];
            #pragma unroll
            for (int mi = 0; mi < 2; mi++)
                #pragma unroll
                for (int ni = 0; ni < 4; ni++)
                    acc[mi][ni] = __builtin_amdgcn_mfma_f32_16x16x32_bf16(af[mi], bfr[ni], acc[mi][ni], 0, 0, 0);
            if (isXBC && wm == 0) {
                bf16x8 h = (kk == 0) ? h0 : h1;
                #pragma unroll
                for (int ni = 0; ni < 4; ni++)
                    hacc[ni] = __builtin_amdgcn_mfma_f32_16x16x32_bf16(h, bfr[ni], hacc[ni], 0, 0, 0);
            }
        }
        __builtin_amdgcn_sched_barrier(0);
        __builtin_amdgcn_s_barrier();       // all reads of buf(kt&1) retired
        __builtin_amdgcn_sched_barrier(0);
        if (kt + 2 < nK) {
            stage(kt + 2);                  // into buf(kt&1), just freed
            if (haloLane) {
                int k0 = (kt + 2) << 6;
                h0 = *(const bf16x8*)(A + (size_t)(m0 - 3 + lr) * K + k0 + lg * 8);
                h1 = *(const bf16x8*)(A + (size_t)(m0 - 3 + lr) * K + k0 + 32 + lg * 8);
            }
        }
    };

    for (int kt = 0; kt < nK; kt += 2) {
        body(kt, hA0, hA1);
        body(kt + 1, hB0, hB1);
    }

    if (isXBC) {
        // ---- fused causal conv(k=4) + SiLU, sliding-window epilogue ----
        short* Tile = SM;   // [131][TS]: rows 0-2 = halo, 3+row = token m0+row
        __syncthreads();    // last tile's ds_reads done before aliasing
        #pragma unroll
        for (int mi = 0; mi < 2; mi++)
            #pragma unroll
            for (int ni = 0; ni < 4; ni++)
                #pragma unroll
                for (int r = 0; r < 4; r++) {
                    int row = wm * 32 + mi * 16 + lg * 4 + r;
                    int col = wn * 64 + ni * 16 + lr;
                    float v = acc[mi][ni][r];
                    float vo = __shfl_xor(v, 1);
                    if (!(lr & 1))
                        *(unsigned*)&Tile[(3 + row) * TS + col] = cvtpk(v, vo);
                }
        if (wm == 0 && lg == 0) {
            #pragma unroll
            for (int ni = 0; ni < 4; ni++)
                #pragma unroll
                for (int r = 0; r < 3; r++)
                    Tile[r * TS + wn * 64 + ni * 16 + lr] = (short)f2bf(hacc[ni][r]);
        }
        __syncthreads();
        int cp = tid & 63, rg = tid >> 6;   // 64 col-pairs x 8 row groups of 16
        int colb = cp * 2;
        int ch = (n0 - 512) + colb;
        float c0w0 = cw[ch * 4], c0w1 = cw[ch * 4 + 1], c0w2 = cw[ch * 4 + 2], c0w3 = cw[ch * 4 + 3];
        float c1w0 = cw[ch * 4 + 4], c1w1 = cw[ch * 4 + 5], c1w2 = cw[ch * 4 + 6], c1w3 = cw[ch * 4 + 7];
        float b0v = cb[ch], b1v = cb[ch + 1];
        int rbase = rg * 16;
        unsigned w0 = *(const unsigned*)&Tile[(rbase + 0) * TS + colb];
        unsigned w1 = *(const unsigned*)&Tile[(rbase + 1) * TS + colb];
        unsigned w2 = *(const unsigned*)&Tile[(rbase + 2) * TS + colb];
        for (int i = 0; i < 16; i++) {
            unsigned w3 = *(const unsigned*)&Tile[(rbase + i + 3) * TS + colb];
            float s0 = b0v, s1 = b1v;
            s0 = fmaf(bf2f((short)(w0 & 0xffffu)), c0w0, s0); s1 = fmaf(bf2f((short)(w0 >> 16)), c1w0, s1);
            s0 = fmaf(bf2f((short)(w1 & 0xffffu)), c0w1, s0); s1 = fmaf(bf2f((short)(w1 >> 16)), c1w1, s1);
            s0 = fmaf(bf2f((short)(w2 & 0xffffu)), c0w2, s0); s1 = fmaf(bf2f((short)(w2 >> 16)), c1w2, s1);
            s0 = fmaf(bf2f((short)(w3 & 0xffffu)), c0w3, s0); s1 = fmaf(bf2f((short)(w3 >> 16)), c1w3, s1);
            s0 = fsilu(s0);
            s1 = fsilu(s1);
            *(unsigned*)&xbc[(size_t)(m0 + rbase + i) * CONVD + ch] = cvtpk(s0, s1);
            w0 = w1; w1 = w2; w2 = w3;
        }
        return;
    }

    #pragma unroll
    for (int mi = 0; mi < 2; mi++) {
        #pragma unroll
        for (int r = 0; r < 4; r++) {
            int row = m0 + wm * 32 + mi * 16 + lg * 4 + r;
            #pragma unroll
            for (int ni = 0; ni < 4; ni++) {
                int col = n0 + wn * 64 + ni * 16 + lr;
                float v = acc[mi][ni][r];
                if (MODE == 0) {
                    if (n0 < 512) {
                        float vo = __shfl_xor(v, 1);
                        if (!(lr & 1))
                            *(unsigned*)&z16[(size_t)row * DINNER + col] = cvtpk(v, vo);
                    } else if (wn == 0 && ni == 0) {
                        dts[(size_t)row * NH + lr] = sp(v + dt_bias[lr]);
                    }
                } else {
                    float vo = __shfl_xor(v, 1);
                    if (!(lr & 1))
                        *(float2*)&outF[(size_t)row * VOCAB + col] = make_float2(v, vo);
                }
            }
        }
    }
}

// ---------------- k_outproj: xf16 = bf16( rms(g)[m] * (g @ Wo'^T) + embed[ids] ) ----------------
// T14 reg-prefetch: next iteration's y/z int4 loads issued before the barrier so their
// latency hides under the barrier+MFMA phase (+16 VGPR, structure otherwise unchanged).
__global__ __launch_bounds__(512) void k_outproj(
    const short* __restrict__ Y16, const short* __restrict__ z16,
    const short* __restrict__ Wo, const int* __restrict__ ids,
    const float* __restrict__ embed, short* __restrict__ xf16) {
    __shared__ __align__(16) short As[8192];
    __shared__ __align__(16) short Bs[8192];
    __shared__ float rmsS[128];
    int tid = threadIdx.x;
    int bid = blockIdx.x;                 // 512 blocks: 8 xcd x 32 m x 2 n
    int slot = bid >> 3;
    int m0 = (((bid & 7) * 32) + (slot >> 1)) << 7;
    int n0 = (slot & 1) << 7;
    int wave = tid >> 6, lane = tid & 63;
    int wm = wave >> 1, wn = wave & 1;
    int lr = lane & 15, lg = lane >> 4;
    const f32x4 zer = {0.f, 0.f, 0.f, 0.f};
    f32x4 acc[2][4];
    #pragma unroll
    for (int i = 0; i < 2; i++)
        #pragma unroll
        for (int j = 0; j < 4; j++) acc[i][j] = zer;

    const int arow = tid >> 2;            // A staging: row 0..127
    const int ac0 = (tid & 3) * 2;        // two 8-short chunks per thread
    const int slo = lane >> 3;
    const int skb = ((lane & 7) ^ slo) << 3;
    float ssq = 0.f;

    union i4u { int4 v; short s[8]; };
    i4u y0u, y1u, z0u, z1u;
    auto loadYZ = [&](int kt) {
        const size_t rbase = (size_t)(m0 + arow) * DINNER + (kt << 6) + ac0 * 8;
        y0u.v = *(const int4*)(Y16 + rbase);
        y1u.v = *(const int4*)(Y16 + rbase + 8);
        z0u.v = *(const int4*)(z16 + rbase);
        z1u.v = *(const int4*)(z16 + rbase + 8);
    };
    loadYZ(0);

    for (int kt = 0; kt < 8; ++kt) {
        int k0 = kt << 6;
        #pragma unroll
        for (int j = 0; j < 2; j++) {
            int row = wave * 16 + j * 8 + slo;
            gload16(Wo + (size_t)(n0 + row) * DINNER + k0 + skb, Bs + (wave * 2 + j) * 512);
        }
        unsigned pk[8];
        #pragma unroll
        for (int e = 0; e < 4; e++) {
            float g0 = bf2f(y0u.s[2*e])     * fsilu(bf2f(z0u.s[2*e]));
            float g1 = bf2f(y0u.s[2*e + 1]) * fsilu(bf2f(z0u.s[2*e + 1]));
            ssq += g0 * g0 + g1 * g1;
            pk[e] = cvtpk(g0, g1);
        }
        #pragma unroll
        for (int e = 0; e < 4; e++) {
            float g0 = bf2f(y1u.s[2*e])     * fsilu(bf2f(z1u.s[2*e]));
            float g1 = bf2f(y1u.s[2*e + 1]) * fsilu(bf2f(z1u.s[2*e + 1]));
            ssq += g0 * g0 + g1 * g1;
            pk[4 + e] = cvtpk(g0, g1);
        }
        *(int4*)&As[arow * 64 + ((ac0 ^ (arow & 7)) << 3)] = *(int4*)&pk[0];
        *(int4*)&As[arow * 64 + (((ac0 + 1) ^ (arow & 7)) << 3)] = *(int4*)&pk[4];
        if (kt + 1 < 8) loadYZ(kt + 1);   // latency hides under barrier+MFMA
        __syncthreads();   // drains gload vmcnt + ds_writes: tile kt ready
        #pragma unroll
        for (int kk = 0; kk < 2; kk++) {
            int sw = (((kk << 2) + lg) ^ (lr & 7)) << 3;
            bf16x8 af[2], bfr[4];
            #pragma unroll
            for (int mi = 0; mi < 2; mi++)
                af[mi] = *(const bf16x8*)&As[(wm * 32 + mi * 16 + lr) * 64 + sw];
            #pragma unroll
            for (int ni = 0; ni < 4; ni++)
                bfr[ni] = *(const bf16x8*)&Bs[(wn * 64 + ni * 16 + lr) * 64 + sw];
            #pragma unroll
            for (int mi = 0; mi < 2; mi++)
                #pragma unroll
                for (int ni = 0; ni < 4; ni++)
                    acc[mi][ni] = __builtin_amdgcn_mfma_f32_16x16x32_bf16(af[mi], bfr[ni], acc[mi][ni], 0, 0, 0);
        }
        __syncthreads();   // all reads done before next overwrite
    }
    // per-row rms: reduce sumsq across the 4 staging threads of each row
    ssq += __shfl_xor(ssq, 1);
    ssq += __shfl_xor(ssq, 2);
    if ((tid & 3) == 0) rmsS[arow] = rsqrtf(ssq * (1.0f / DINNER) + 1e-5f);
    __syncthreads();

    #pragma unroll
    for (int mi = 0; mi < 2; mi++) {
        #pragma unroll
        for (int r = 0; r < 4; r++) {
            int rl = wm * 32 + mi * 16 + lg * 4 + r;
            int row = m0 + rl;
            int id = ids[row];
            float rm = rmsS[rl];
            #pragma unroll
            for (int ni = 0; ni < 4; ni++) {
                int col = n0 + wn * 64 + ni * 16 + lr;
                float v = acc[mi][ni][r] * rm;
                float vo = __shfl_xor(v, 1);
                if (!(lr & 1)) {
                    float2 res = *(const float2*)&embed[(size_t)id * DMODEL + col];
                    *(unsigned*)&xf16[(size_t)row * DMODEL + col] = cvtpk(v + res.x, vo + res.y);
                }
            }
        }
    }
}

// ---------------- k_states: per (b,c,hg): chunk states, bulk-staged x, swizzled st16 write ----------------
__global__ __launch_bounds__(256) void k_states(const short* __restrict__ xbc, const float* __restrict__ dts,
                                                const float* __restrict__ A_log,
                                                short* __restrict__ st16,
                                                float* __restrict__ acs_g, float* __restrict__ cdec) {
    __shared__ short BsB[64 * 72];   // B[k][n]
    __shared__ short BT[64 * 72];    // B^T[n][k], built once
    __shared__ short XdS[32 * 72];   // Xd[p][k] per head (padded, MFMA operand)
    __shared__ __align__(16) short XKP[64 * 32];  // raw x tile [k][p], gload16 target
    __shared__ float dkS[HGRP][64];
    __shared__ float dtS[64];
    int tid = threadIdx.x;
    int bid = blockIdx.x;
    int hg = bid & 3;
    int bc = bid >> 2;
    int b = bc >> 6, c = bc & 63;
    int h0 = hg * HGRP;
    size_t tbase = (size_t)b * SEQ + (size_t)c * 64;
    int wave = tid >> 6, lane = tid & 63;
    int lr = lane & 15, lg = lane >> 4;

    for (int i = tid; i < 64 * 64; i += 256) {
        int q = i >> 6, n = i & 63;
        BsB[q * 72 + n] = xbc[(tbase + q) * CONVD + DINNER + n];
    }
    {
        int h = h0 + wave;
        float Ah = -__expf(A_log[h]);
        float v = dts[(tbase + lane) * NH + h] * Ah;
        #pragma unroll
        for (int off = 1; off < 64; off <<= 1) {
            float o = __shfl_up(v, off);
            if (lane >= off) v += o;
        }
        acs_g[(((size_t)(b * NH + h)) * 64 + c) * 64 + lane] = v;
        float alast = __shfl(v, 63);
        dkS[wave][lane] = __expf(alast - v);
        if (lane == 0) cdec[(b * NH + h) * 64 + c] = __expf(alast);
    }
    __syncthreads();
    for (int i = tid; i < 64 * 64; i += 256) {
        int k = i >> 6, n = i & 63;
        BT[n * 72 + k] = BsB[k * 72 + n];
    }

    for (int hh = 0; hh < HGRP; hh++) {
        int h = h0 + hh;
        {
            int s = wave * 64 + lane;
            gload16(xbc + (tbase + (s >> 2)) * CONVD + h * HD + (s & 3) * 8, XKP + wave * 512);
        }
        if (tid < 64) dtS[tid] = dts[(tbase + tid) * NH + h];
        __syncthreads();
        for (int i = tid; i < 2048; i += 256) {
            int p = i & 31, k = i >> 5;
            XdS[p * 72 + k] = (short)f2bf(bf2f(XKP[k * 32 + p]) * dtS[k] * dkS[hh][k]);
        }
        __syncthreads();
        {
            int ptile = wave & 1;
            bf16x8 a0 = *(const bf16x8*)&XdS[(ptile * 16 + lr) * 72 + lg * 8];
            bf16x8 a1 = *(const bf16x8*)&XdS[(ptile * 16 + lr) * 72 + 32 + lg * 8];
            size_t base = ((size_t)bc * NH + h) * 2048;
            #pragma unroll
            for (int j = 0; j < 2; j++) {
                int nt = (wave >> 1) * 2 + j;
                bf16x8 b0 = *(const bf16x8*)&BT[(nt * 16 + lr) * 72 + lg * 8];
                bf16x8 b1 = *(const bf16x8*)&BT[(nt * 16 + lr) * 72 + 32 + lg * 8];
                f32x4 z = {0.f, 0.f, 0.f, 0.f};
                z = __builtin_amdgcn_mfma_f32_16x16x32_bf16(a0, b0, z, 0, 0, 0);
                z = __builtin_amdgcn_mfma_f32_16x16x32_bf16(a1, b1, z, 0, 0, 0);
                #pragma unroll
                for (int r = 0; r < 4; r++) {
                    int p = ptile * 16 + lg * 4 + r;
                    float v = z[r];
                    float vo = __shfl_xor(v, 1);
                    if (!(lr & 1)) {
                        int chunk = (nt << 1) | (lr >> 3);
                        *(unsigned*)&st16[base + p * 64 + ((chunk ^ (p & 7)) << 3) + (lr & 7)] = cvtpk(v, vo);
                    }
                }
            }
        }
        __syncthreads();
    }
}

// ---------------- k_scan: sequential inter-chunk scan on bf16 states (fp32 accum) ----------------
__global__ __launch_bounds__(256) void k_scan(unsigned* __restrict__ st32, const float* __restrict__ cdec) {
    int bid = blockIdx.x;           // BATCH*NH*4
    int bh = bid >> 2, seg = bid & 3;
    int b = bh >> 4, h = bh & 15;
    int off = seg * 256 + threadIdx.x;   // u32 index within 1024
    float p0 = 0.f, p1 = 0.f;
    for (int c = 0; c < 64; c++) {
        float dec = cdec[bh * 64 + c];
        size_t idx = ((((size_t)b * 64 + c) * NH) + h) * 1024 + off;
        unsigned v = st32[idx];
        float s0 = bf2f((short)(v & 0xffffu));
        float s1 = bf2f((short)(v >> 16));
        st32[idx] = cvtpk(p0, p1);
        p0 = fmaf(dec, p0, s0);
        p1 = fmaf(dec, p1, s1);
    }
}

// ---------------- k_y: Y16 = Y_diag + exp(acs)*(C . prev^T) + D*x ----------------
__global__ __launch_bounds__(256) void k_y(const short* __restrict__ xbc, const float* __restrict__ dts,
                                           const short* __restrict__ st16, const float* __restrict__ acs_g,
                                           const float* __restrict__ D_skip, short* __restrict__ Y16) {
    __shared__ short CsB[64 * 72];   // C[q][n], live throughout
    __shared__ short Wsh[64 * 72];   // B at load; W per head after M
    __shared__ short XtS[32 * 72];   // Xt[p][k] per head (padded, MFMA operand)
    __shared__ __align__(16) short PtL[32 * 64];  // prev tile, linear copy of (swizzled) st16
    __shared__ __align__(16) short XKP[64 * 32];  // raw x tile [k][p]
    __shared__ float acsH[64];
    __shared__ float dtS[64];
    int tid = threadIdx.x;
    int bid = blockIdx.x;
    int hg = bid & 3;
    int bc = bid >> 2;
    int b = bc >> 6, c = bc & 63;
    int h0 = hg * HGRP;
    size_t tbase = (size_t)b * SEQ + (size_t)c * 64;
    int wave = tid >> 6, lane = tid & 63;
    int lr = lane & 15, lg = lane >> 4;

    for (int i = tid; i < 64 * 64; i += 256) {
        int q = i >> 6, n = i & 63;
        const short* rowp = xbc + (tbase + q) * CONVD + DINNER;
        Wsh[q * 72 + n] = rowp[n];            // B (consumed by M, then reused as W)
        CsB[q * 72 + n] = rowp[DSTATE + n];   // C
    }
    __syncthreads();

    // M = C . B^T : wave owns q-strip of 16 rows, kept in regs
    f32x4 macc[4];
    bf16x8 ca0 = *(const bf16x8*)&CsB[(wave * 16 + lr) * 72 + lg * 8];
    bf16x8 ca1 = *(const bf16x8*)&CsB[(wave * 16 + lr) * 72 + 32 + lg * 8];
    {
        #pragma unroll
        for (int ct = 0; ct < 4; ct++) {
            bf16x8 b0 = *(const bf16x8*)&Wsh[(ct * 16 + lr) * 72 + lg * 8];
            bf16x8 b1 = *(const bf16x8*)&Wsh[(ct * 16 + lr) * 72 + 32 + lg * 8];
            f32x4 z = {0.f, 0.f, 0.f, 0.f};
            z = __builtin_amdgcn_mfma_f32_16x16x32_bf16(ca0, b0, z, 0, 0, 0);
            z = __builtin_amdgcn_mfma_f32_16x16x32_bf16(ca1, b1, z, 0, 0, 0);
            macc[ct] = z;
        }
    }
    __syncthreads();   // all waves done reading B before Wsh is overwritten

    for (int hh = 0; hh < HGRP; hh++) {
        int h = h0 + hh;
        // phase 1: issue bulk loads + stage per-head scalars
        {
            int s = wave * 64 + lane;
            gload16(xbc + (tbase + (s >> 2)) * CONVD + h * HD + (s & 3) * 8, XKP + wave * 512);
            gload16(st16 + ((size_t)bc * NH + h) * 2048 + s * 8, PtL + wave * 512);
        }
        if (tid < 64) {
            acsH[tid] = acs_g[(((size_t)(b * NH + h)) * 64 + c) * 64 + tid];
            dtS[tid] = dts[(tbase + tid) * NH + h];
        }
        __syncthreads();
        // phase 2: W build (wave-local rows) + Xt transpose
        #pragma unroll
        for (int ct = 0; ct < 4; ct++) {
            int k = ct * 16 + lr;
            #pragma unroll
            for (int r = 0; r < 4; r++) {
                int q = wave * 16 + lg * 4 + r;
                float wv = 0.f;
                if (k <= q) wv = macc[ct][r] * __expf(acsH[q] - acsH[k]);
                float wo = __shfl_xor(wv, 1);
                if (!(lr & 1))
                    *(unsigned*)&Wsh[q * 72 + k] = cvtpk(wv, wo);
            }
        }
        for (int i = tid; i < 2048; i += 256) {
            int p = i & 31, k = i >> 5;
            XtS[p * 72 + k] = (short)f2bf(bf2f(XKP[k * 32 + p]) * dtS[k]);
        }
        __syncthreads();
        // phase 3: MFMAs + Y write
        float eq[4];
        #pragma unroll
        for (int r = 0; r < 4; r++) eq[r] = __expf(acsH[wave * 16 + lg * 4 + r]);
        float dsk = D_skip[h];
        bf16x8 wa0 = *(const bf16x8*)&Wsh[(wave * 16 + lr) * 72 + lg * 8];
        bf16x8 wa1 = *(const bf16x8*)&Wsh[(wave * 16 + lr) * 72 + 32 + lg * 8];
        #pragma unroll
        for (int pt = 0; pt < 2; pt++) {
            int p = pt * 16 + lr;
            bf16x8 xb0 = *(const bf16x8*)&XtS[p * 72 + lg * 8];
            bf16x8 xb1 = *(const bf16x8*)&XtS[p * 72 + 32 + lg * 8];
            f32x4 zd = {0.f, 0.f, 0.f, 0.f};
            zd = __builtin_amdgcn_mfma_f32_16x16x32_bf16(wa0, xb0, zd, 0, 0, 0);
            zd = __builtin_amdgcn_mfma_f32_16x16x32_bf16(wa1, xb1, zd, 0, 0, 0);
            bf16x8 pb0 = *(const bf16x8*)&PtL[p * 64 + ((lg ^ (p & 7)) << 3)];
            bf16x8 pb1 = *(const bf16x8*)&PtL[p * 64 + (((lg + 4) ^ (p & 7)) << 3)];
            f32x4 zo = {0.f, 0.f, 0.f, 0.f};
            zo = __builtin_amdgcn_mfma_f32_16x16x32_bf16(ca0, pb0, zo, 0, 0, 0);
            zo = __builtin_amdgcn_mfma_f32_16x16x32_bf16(ca1, pb1, zo, 0, 0, 0);
            #pragma unroll
            for (int r = 0; r < 4; r++) {
                int q = wave * 16 + lg * 4 + r;
                float xv = bf2f(XKP[q * 32 + p]);
                float v = zd[r] + eq[r] * zo[r] + dsk * xv;
                float vo = __shfl_xor(v, 1);
                if (!(lr & 1))
                    *(unsigned*)&Y16[((tbase + q) * NH + h) * HD + p] = cvtpk(v, vo);
            }
        }
        __syncthreads();   // protect buffers before next head overwrite
    }
}

extern "C" void kernel_launch(void* const* d_in, const int* in_sizes, int n_in,
                              void* d_out, int out_size, void* d_ws, size_t ws_size,
                              hipStream_t stream) {
    const int*   ids        = (const int*)d_in[0];
    const float* embed_w    = (const float*)d_in[1];
    const float* in_proj_w  = (const float*)d_in[2];
    const float* conv_w     = (const float*)d_in[3];
    const float* conv_b     = (const float*)d_in[4];
    const float* A_log      = (const float*)d_in[5];
    const float* D_skip     = (const float*)d_in[6];
    const float* dt_bias    = (const float*)d_in[7];
    const float* gate_w     = (const float*)d_in[8];
    const float* out_proj_w = (const float*)d_in[9];
    const float* norm_w     = (const float*)d_in[10];
    float* out = (float*)d_out;

    if (ws_size < WS_FLOATS * sizeof(float)) {
        k_diag<<<1, 64, 0, stream>>>(out, (float)(ws_size >> 20));
        return;
    }

    float* ws   = (float*)d_ws;
    short* u16  = (short*)(ws + U16_OFF);
    short* z16  = (short*)(ws + Z16_OFF);
    short* xbc  = (short*)(ws + XBC_OFF);
    float* dts  = ws + DTS_OFF;
    float* acs  = ws + ACS_OFF;
    float* cdec = ws + CDEC_OFF;
    short* Wp   = (short*)(ws + WP_OFF);
    short* Wo   = (short*)(ws + WO_OFF);
    short* We   = (short*)(ws + WE_OFF);
    short* st16 = (short*)(ws + UNION_OFF);                 // bf16 states (swizzled)
    short* Y16  = (short*)(ws + UNION_OFF + Y16_SUB);       // bf16 Y (live through k_outproj)
    short* xf16 = (short*)(ws + UNION_OFF);                 // aliases dead st16

    k_cvt<<<(NPAD * DMODEL + 255) / 256, 256, 0, stream>>>(in_proj_w, Wp, DPROJ * DMODEL, NPAD * DMODEL);
    k_cvt_gate<<<(DMODEL * DINNER + 255) / 256, 256, 0, stream>>>(out_proj_w, gate_w, Wo, DMODEL * DINNER);
    k_cvt<<<(VOCAB * DMODEL + 255) / 256, 256, 0, stream>>>(embed_w, We, VOCAB * DMODEL, VOCAB * DMODEL);
    k_embed<<<TOK, 64, 0, stream>>>(ids, embed_w, norm_w, u16);
    k_gemm_mfma<0><<<(NPAD / 128) * 256, 512, 0, stream>>>(
        u16, Wp, DMODEL, nullptr, z16, xbc, dts, dt_bias, conv_w, conv_b);
    k_states<<<BATCH * 64 * 4, 256, 0, stream>>>(xbc, dts, A_log, st16, acs, cdec);
    k_scan<<<BATCH * NH * 4, 256, 0, stream>>>((unsigned*)st16, cdec);
    k_y<<<BATCH * 64 * 4, 256, 0, stream>>>(xbc, dts, st16, acs, D_skip, Y16);
    k_outproj<<<(DMODEL / 128) * 256, 512, 0, stream>>>(Y16, z16, Wo, ids, embed_w, xf16);
    k_gemm_mfma<2><<<(VOCAB / 128) * 256, 512, 0, stream>>>(
        xf16, We, DMODEL, out, nullptr, nullptr, nullptr, nullptr, nullptr, nullptr);
}